// Round 1
// baseline (622.800 us; speedup 1.0000x reference)
//
#include <hip/hip_runtime.h>
#include <math.h>

// Problem constants (fixed by the reference)
#define Bn 64
#define Tn 512
#define Dn 256
#define Mn 1024
#define Nn (Bn * Tn)      // 32768
#define RB 8              // rows per block in fused kernel

// ---------------- workspace layout (float offsets) ----------------
#define OFF_APH   0                  // [64*1024] f32  sum over T of softmax probs (audio)
#define OFF_EPH   65536              // [64*1024] f32  (eeg)
#define OFF_ACNT  131072             // [64*1024] u32  hard-assign counts (audio)
#define OFF_ECNT  196608             // [64*1024] u32  (eeg)
#define OFF_LAT   262144             // [4] f32        latent squared-diff sums
#define ZERO_FLOATS 262656           // zero region [0, ZERO_FLOATS)
#define OFF_SE2   262656             // [1024] f32     sum(emb^2) per code
#define OFF_EMBT  263680             // [256*1024] f32 transposed embedding
#define OFF_APHN  525824             // [64*1024] f32  normalized a_ph
#define OFF_EPHN  591360             // [64*1024] f32  normalized e_ph
#define OFF_LA    656896             // [64*1024] f32  log(a_ph+1e-10)
#define OFF_LE    722432             // [64*1024] f32  log(e_ph+1e-10)
#define OFF_SCODE 787968             // [64*64] f32
// total ~792064 floats = 3.17 MB

#define OUT_SCALARS ((size_t)2 * Nn * Dn)   // 16777216

// ---------------- prep: transpose embedding + per-code ||e||^2 ----------------
__global__ __launch_bounds__(256) void kPrep(const float* __restrict__ emb,
                                             float* __restrict__ ws) {
  __shared__ float tile[32][260];
  float* embT = ws + OFF_EMBT;
  float* se2  = ws + OFF_SE2;
  const int tid = threadIdx.x;
  const int m0  = blockIdx.x * 32;
  for (int i = tid; i < 32 * 64; i += 256) {
    int r = i >> 6, c = i & 63;
    float4 v = ((const float4*)(emb + (size_t)(m0 + r) * Dn))[c];
    tile[r][c * 4 + 0] = v.x; tile[r][c * 4 + 1] = v.y;
    tile[r][c * 4 + 2] = v.z; tile[r][c * 4 + 3] = v.w;
  }
  __syncthreads();
  if (tid < 32) {
    float s = 0.f;
    for (int k = 0; k < Dn; ++k) { float v = tile[tid][k]; s = fmaf(v, v, s); }
    se2[m0 + tid] = s;
  }
  const int g = tid & 31, kq = tid >> 5;
  for (int o = 0; o < 256; o += 8) {
    int k = o + kq;
    embT[(size_t)k * Mn + m0 + g] = tile[g][k];
  }
}

// ---------------- fused: distances + softmax + argmin + gather ----------------
__global__ __launch_bounds__(256, 3) void kA(const float* __restrict__ audio,
                                             const float* __restrict__ eeg,
                                             const float* __restrict__ emb,
                                             float* __restrict__ out,
                                             float* __restrict__ ws) {
  const int tid = threadIdx.x;
  const int n0  = blockIdx.x * RB;
  const int b   = n0 / Tn;
  const float* embT = ws + OFF_EMBT;
  const float* se2g = ws + OFF_SE2;

  __shared__ float dm[RB][1032];   // dot products for current modality (stride 1032 breaks bank patterns)
  __shared__ float se2l[Mn];
  __shared__ float sx2s[2][RB];
  __shared__ float rowL[RB], rowInvZ[RB], rowMin[RB];
  __shared__ int   rowIdx[RB];

  for (int i = tid; i < Mn; i += 256) se2l[i] = se2g[i];

  if (tid < RB) {
    const float* x = audio + (size_t)(n0 + tid) * Dn;
    float s = 0.f;
    for (int k = 0; k < Dn; ++k) s = fmaf(x[k], x[k], s);
    sx2s[0][tid] = s;
  } else if (tid >= 32 && tid < 32 + RB) {
    const float* x = eeg + (size_t)(n0 + tid - 32) * Dn;
    float s = 0.f;
    for (int k = 0; k < Dn; ++k) s = fmaf(x[k], x[k], s);
    sx2s[1][tid - 32] = s;
  }

  const int m0 = tid * 4;           // this thread owns codes m0..m0+3
  float accA[RB][4], accE[RB][4];
  #pragma unroll
  for (int r = 0; r < RB; ++r)
    #pragma unroll
    for (int j = 0; j < 4; ++j) { accA[r][j] = 0.f; accE[r][j] = 0.f; }

  for (int k4 = 0; k4 < 64; ++k4) {
    float ev[4][4];
    #pragma unroll
    for (int i = 0; i < 4; ++i) {
      float4 t = *(const float4*)(embT + (size_t)(k4 * 4 + i) * Mn + m0);
      ev[i][0] = t.x; ev[i][1] = t.y; ev[i][2] = t.z; ev[i][3] = t.w;
    }
    #pragma unroll
    for (int r = 0; r < RB; ++r) {
      float4 ta = ((const float4*)(audio + (size_t)(n0 + r) * Dn))[k4];
      float4 te = ((const float4*)(eeg  + (size_t)(n0 + r) * Dn))[k4];
      float xa[4] = {ta.x, ta.y, ta.z, ta.w};
      float xe[4] = {te.x, te.y, te.z, te.w};
      #pragma unroll
      for (int i = 0; i < 4; ++i) {
        #pragma unroll
        for (int j = 0; j < 4; ++j) {
          accA[r][j] = fmaf(xa[i], ev[i][j], accA[r][j]);
          accE[r][j] = fmaf(xe[i], ev[i][j], accE[r][j]);
        }
      }
    }
  }

  #pragma unroll
  for (int mod = 0; mod < 2; ++mod) {
    __syncthreads();   // also covers initial staging barrier on mod==0
    #pragma unroll
    for (int r = 0; r < RB; ++r) {
      float4 w;
      w.x = (mod == 0) ? accA[r][0] : accE[r][0];
      w.y = (mod == 0) ? accA[r][1] : accE[r][1];
      w.z = (mod == 0) ? accA[r][2] : accE[r][2];
      w.w = (mod == 0) ? accA[r][3] : accE[r][3];
      *(float4*)(&dm[r][tid * 4]) = w;
    }
    __syncthreads();

    const int rr = tid >> 5, g = tid & 31;
    const float sxr = sx2s[mod][rr];

    // E1: row min of (se2[m] - 2*dot) + first-occurrence argmin
    {
      float vmin = 3.0e38f; int imin = Mn;
      for (int i = 0; i < 32; ++i) {
        int m = g + (i << 5);
        float part = fmaf(-2.f, dm[rr][m], se2l[m]);
        if (part < vmin) { vmin = part; imin = m; }
      }
      #pragma unroll
      for (int off = 1; off < 32; off <<= 1) {
        float ov = __shfl_xor(vmin, off);
        int   oi = __shfl_xor(imin, off);
        if (ov < vmin || (ov == vmin && oi < imin)) { vmin = ov; imin = oi; }
      }
      if (g == 0) {
        rowMin[rr] = vmin; rowIdx[rr] = imin;
        rowL[rr] = sqrtf(fmaxf(vmin + sxr, 0.f));
      }
    }
    __syncthreads();

    // E2: softmax denominator Z per row
    {
      float Lr = rowL[rr];
      float z = 0.f;
      for (int i = 0; i < 32; ++i) {
        int m = g + (i << 5);
        float part = fmaf(-2.f, dm[rr][m], se2l[m]);
        float s = sqrtf(fmaxf(part + sxr, 0.f));
        z += __expf(Lr - s);
      }
      #pragma unroll
      for (int off = 1; off < 32; off <<= 1) z += __shfl_xor(z, off);
      if (g == 0) rowInvZ[rr] = 1.f / z;
    }
    __syncthreads();

    // E3: accumulate probabilities into ph[b][m]
    {
      float* ph = ws + ((mod == 0) ? OFF_APH : OFF_EPH);
      float psum[4] = {0.f, 0.f, 0.f, 0.f};
      float c0 = se2l[m0 + 0], c1 = se2l[m0 + 1], c2 = se2l[m0 + 2], c3 = se2l[m0 + 3];
      for (int r = 0; r < RB; ++r) {
        float Lr = rowL[r], iz = rowInvZ[r], sxr2 = sx2s[mod][r];
        float4 dd = *(const float4*)(&dm[r][m0]);
        psum[0] += __expf(Lr - sqrtf(fmaxf(fmaf(-2.f, dd.x, c0) + sxr2, 0.f))) * iz;
        psum[1] += __expf(Lr - sqrtf(fmaxf(fmaf(-2.f, dd.y, c1) + sxr2, 0.f))) * iz;
        psum[2] += __expf(Lr - sqrtf(fmaxf(fmaf(-2.f, dd.z, c2) + sxr2, 0.f))) * iz;
        psum[3] += __expf(Lr - sqrtf(fmaxf(fmaf(-2.f, dd.w, c3) + sxr2, 0.f))) * iz;
      }
      atomicAdd(&ph[b * Mn + m0 + 0], psum[0]);
      atomicAdd(&ph[b * Mn + m0 + 1], psum[1]);
      atomicAdd(&ph[b * Mn + m0 + 2], psum[2]);
      atomicAdd(&ph[b * Mn + m0 + 3], psum[3]);
    }

    // counts for mode/perplexity
    if (tid < RB) {
      unsigned* cnt = (unsigned*)(ws + ((mod == 0) ? OFF_ACNT : OFF_ECNT));
      atomicAdd(&cnt[b * Mn + rowIdx[tid]], 1u);
    }

    // gather quantized rows (straight-through value == quantized)
    {
      float* qout = out + (size_t)mod * Nn * Dn;
      int r = tid >> 5, c = tid & 31;
      int qi = rowIdx[r];
      const float4* src = (const float4*)(emb + (size_t)qi * Dn);
      float4* dst = (float4*)(qout + (size_t)(n0 + r) * Dn);
      dst[c] = src[c];
      dst[c + 32] = src[c + 32];
    }
  }
}

// ---------------- commitment-loss sums ----------------
__global__ __launch_bounds__(256) void kB(const float* __restrict__ a,
                                          const float* __restrict__ e,
                                          const float* __restrict__ out,
                                          float* __restrict__ ws) {
  float* lat = ws + OFF_LAT;
  const float4* A  = (const float4*)a;
  const float4* E  = (const float4*)e;
  const float4* QA = (const float4*)out;
  const float4* QE = (const float4*)(out + (size_t)Nn * Dn);
  float s0 = 0.f, s1 = 0.f, s2 = 0.f, s3 = 0.f;
  const int total = Nn * Dn / 4;
  for (int i = blockIdx.x * 256 + threadIdx.x; i < total; i += gridDim.x * 256) {
    float4 av = A[i], evv = E[i], qa = QA[i], qe = QE[i];
    { float t0=av.x-qa.x, t1=av.y-qa.y, t2=av.z-qa.z, t3=av.w-qa.w; s0 += t0*t0+t1*t1+t2*t2+t3*t3; }
    { float t0=av.x-qe.x, t1=av.y-qe.y, t2=av.z-qe.z, t3=av.w-qe.w; s1 += t0*t0+t1*t1+t2*t2+t3*t3; }
    { float t0=evv.x-qe.x, t1=evv.y-qe.y, t2=evv.z-qe.z, t3=evv.w-qe.w; s2 += t0*t0+t1*t1+t2*t2+t3*t3; }
    { float t0=evv.x-qa.x, t1=evv.y-qa.y, t2=evv.z-qa.z, t3=evv.w-qa.w; s3 += t0*t0+t1*t1+t2*t2+t3*t3; }
  }
  __shared__ float red[4][4];
  int lane = threadIdx.x & 63, w = threadIdx.x >> 6;
  #pragma unroll
  for (int off = 32; off > 0; off >>= 1) {
    s0 += __shfl_down(s0, off); s1 += __shfl_down(s1, off);
    s2 += __shfl_down(s2, off); s3 += __shfl_down(s3, off);
  }
  if (lane == 0) { red[w][0] = s0; red[w][1] = s1; red[w][2] = s2; red[w][3] = s3; }
  __syncthreads();
  if (threadIdx.x < 4) {
    float t = red[0][threadIdx.x] + red[1][threadIdx.x] + red[2][threadIdx.x] + red[3][threadIdx.x];
    atomicAdd(&lat[threadIdx.x], t);
  }
}

// ---------------- normalize ph + log tables ----------------
__global__ __launch_bounds__(256) void kC0(float* __restrict__ ws) {
  int i = blockIdx.x * 256 + threadIdx.x;   // < 65536
  float a = ws[OFF_APH + i] * (1.f / 512.f);
  float e = ws[OFF_EPH + i] * (1.f / 512.f);
  ws[OFF_APHN + i] = a;
  ws[OFF_EPHN + i] = e;
  ws[OFF_LA + i] = logf(a + 1e-10f);
  ws[OFF_LE + i] = logf(e + 1e-10f);
}

// ---------------- Scode = a_ph @ log(e_ph.T) + e_ph @ log(a_ph.T) ----------------
__global__ __launch_bounds__(256) void kC1(float* __restrict__ ws) {
  const int i = blockIdx.x;          // row of Scode
  const int tid = threadIdx.x;
  const int j = tid >> 2, q = tid & 3;
  const float* ai  = ws + OFF_APHN + (size_t)i * Mn;
  const float* ei  = ws + OFF_EPHN + (size_t)i * Mn;
  const float* lej = ws + OFF_LE + (size_t)j * Mn;
  const float* laj = ws + OFF_LA + (size_t)j * Mn;
  float s = 0.f;
  for (int m = q * 256; m < (q + 1) * 256; ++m)
    s += ai[m] * lej[m] + ei[m] * laj[m];
  s += __shfl_xor(s, 1);
  s += __shfl_xor(s, 2);
  if (q == 0) ws[OFF_SCODE + i * 64 + j] = s;
}

// ---------------- finalize: cmcm, losses, perplexities, modes ----------------
__global__ __launch_bounds__(256) void kC2(float* __restrict__ ws, float* __restrict__ out) {
  __shared__ float sc[4096];
  __shared__ float red[256];
  __shared__ float rterm[64];
  __shared__ float maxv;
  const int tid = threadIdx.x;
  const float* scode = ws + OFF_SCODE;
  for (int i = tid; i < 4096; i += 256) sc[i] = scode[i];
  __syncthreads();

  float mx = -3.0e38f;
  for (int i = tid; i < 4096; i += 256) mx = fmaxf(mx, -sc[i]);
  red[tid] = mx; __syncthreads();
  for (int s = 128; s > 0; s >>= 1) {
    if (tid < s) red[tid] = fmaxf(red[tid], red[tid + s]);
    __syncthreads();
  }
  if (tid == 0) maxv = red[0];
  __syncthreads();
  const float Max = maxv;

  if (tid < 64) {
    float rs = 0.f;
    for (int j = 0; j < 64; ++j) rs += expf(sc[tid * 64 + j] + Max);
    float dg = expf(sc[tid * 64 + tid] + Max);
    rterm[tid] = logf(dg / (rs + 1e-5f));
  }
  __syncthreads();
  if (tid == 0) {
    float s = 0.f;
    for (int i = 0; i < 64; ++i) s += rterm[i];
    float Lcmcm = -s / 64.f;
    out[OUT_SCALARS + 4] = 0.5f * Lcmcm;
  }
  if (tid == 1) {
    const float* lat = ws + OFF_LAT;
    const float inv = 1.f / 8388608.f;
    float a_e = lat[0] * inv, ae = lat[1] * inv, e_e = lat[2] * inv, ea = lat[3] * inv;
    out[OUT_SCALARS + 0] = 0.25f * (2.f * a_e + ae);
    out[OUT_SCALARS + 1] = 0.25f * (2.f * e_e + ea);
  }

  // perplexities from counts
  const unsigned* acnt = (const unsigned*)(ws + OFF_ACNT);
  const unsigned* ecnt = (const unsigned*)(ws + OFF_ECNT);
  float enta = 0.f, ente = 0.f;
  for (int mm = tid; mm < Mn; mm += 256) {
    unsigned ta = 0, te = 0;
    for (int bb = 0; bb < Bn; ++bb) { ta += acnt[bb * Mn + mm]; te += ecnt[bb * Mn + mm]; }
    float av = (float)ta * (1.f / 32768.f);
    float ev = (float)te * (1.f / 32768.f);
    enta += av * logf(av + 1e-10f);
    ente += ev * logf(ev + 1e-10f);
  }
  __syncthreads(); red[tid] = enta; __syncthreads();
  for (int s = 128; s > 0; s >>= 1) { if (tid < s) red[tid] += red[tid + s]; __syncthreads(); }
  if (tid == 0) out[OUT_SCALARS + 2] = expf(-red[0]);
  __syncthreads(); red[tid] = ente; __syncthreads();
  for (int s = 128; s > 0; s >>= 1) { if (tid < s) red[tid] += red[tid + s]; __syncthreads(); }
  if (tid == 0) out[OUT_SCALARS + 3] = expf(-red[0]);

  // per-sample modes (first-max) and equal_num
  float eq = 0.f;
  if (tid < 64) {
    unsigned bestA = 0; int ia = 0;
    unsigned bestE = 0; int ie = 0;
    for (int m = 0; m < Mn; ++m) {
      unsigned ca = acnt[tid * Mn + m];
      if (ca > bestA) { bestA = ca; ia = m; }
      unsigned ce = ecnt[tid * Mn + m];
      if (ce > bestE) { bestE = ce; ie = m; }
    }
    eq = (ia == ie) ? 1.f : 0.f;
  }
  __syncthreads(); red[tid] = eq; __syncthreads();
  for (int s = 128; s > 0; s >>= 1) { if (tid < s) red[tid] += red[tid + s]; __syncthreads(); }
  if (tid == 0) out[OUT_SCALARS + 5] = red[0];
}

extern "C" void kernel_launch(void* const* d_in, const int* in_sizes, int n_in,
                              void* d_out, int out_size, void* d_ws, size_t ws_size,
                              hipStream_t stream) {
  const float* audio = (const float*)d_in[0];
  const float* eeg   = (const float*)d_in[1];
  const float* emb   = (const float*)d_in[2];
  float* out = (float*)d_out;
  float* ws  = (float*)d_ws;
  (void)in_sizes; (void)n_in; (void)out_size; (void)ws_size;

  hipMemsetAsync(d_ws, 0, (size_t)ZERO_FLOATS * sizeof(float), stream);
  hipLaunchKernelGGL(kPrep, dim3(32), dim3(256), 0, stream, emb, ws);
  hipLaunchKernelGGL(kA, dim3(Nn / RB), dim3(256), 0, stream, audio, eeg, emb, out, ws);
  hipLaunchKernelGGL(kB, dim3(1024), dim3(256), 0, stream, audio, eeg, out, ws);
  hipLaunchKernelGGL(kC0, dim3(256), dim3(256), 0, stream, ws);
  hipLaunchKernelGGL(kC1, dim3(64), dim3(256), 0, stream, ws);
  hipLaunchKernelGGL(kC2, dim3(1), dim3(256), 0, stream, ws, out);
}

// Round 2
// 402.938 us; speedup vs baseline: 1.5456x; 1.5456x over previous
//
#include <hip/hip_runtime.h>
#include <math.h>

#define Bn 64
#define Tn 512
#define Dn 256
#define Mn 1024
#define Nn (Bn * Tn)              // 32768
#define NnDn ((size_t)Nn * Dn)

typedef __attribute__((ext_vector_type(8))) short short8v;
typedef __attribute__((ext_vector_type(4))) float float4v;

// ---------------- workspace layout (float offsets) ----------------
#define OFF_APH   0               // [64*1024] f32
#define OFF_EPH   65536           // [64*1024] f32
#define OFF_ACNT  131072          // [64*1024] u32
#define OFF_ECNT  196608          // [64*1024] u32
#define OFF_LAT   262144          // [4] f32
#define ZERO_FLOATS 262656
#define OFF_SE2   262656          // [1024] f32
#define OFF_EH    263680          // 1024*256 ushort (131072 float slots)
#define OFF_EL    394752          // 1024*256 ushort
#define OFF_APHN  525824
#define OFF_EPHN  591360
#define OFF_LA    656896
#define OFF_LE    722432
#define OFF_SCODE 787968
#define OUT_SCALARS ((size_t)2 * Nn * Dn)

__device__ __forceinline__ unsigned short bf16hi(float x) {
  unsigned u = __float_as_uint(x);
  return (unsigned short)((u + 0x7FFFu + ((u >> 16) & 1u)) >> 16);
}
__device__ __forceinline__ float bf16tof(unsigned short h) {
  return __uint_as_float(((unsigned)h) << 16);
}

// ---------------- prep: embedding -> bf16 hi/lo + ||e||^2 ----------------
__global__ __launch_bounds__(256) void kPrepE(const float* __restrict__ emb,
                                              float* __restrict__ ws) {
  unsigned short* Eh = (unsigned short*)(ws + OFF_EH);
  unsigned short* El = (unsigned short*)(ws + OFF_EL);
  float* se2 = ws + OFF_SE2;
  const int tid = threadIdx.x;
  const int row = blockIdx.x * 32 + (tid >> 3);
  const int sub = tid & 7;
  const float* src = emb + (size_t)row * Dn + sub * 32;
  unsigned short* dh = Eh + (size_t)row * Dn + sub * 32;
  unsigned short* dl = El + (size_t)row * Dn + sub * 32;
  float s2 = 0.f;
  for (int g = 0; g < 4; ++g) {
    float4 v0 = ((const float4*)src)[g * 2];
    float4 v1 = ((const float4*)src)[g * 2 + 1];
    float xs[8] = {v0.x, v0.y, v0.z, v0.w, v1.x, v1.y, v1.z, v1.w};
    short8v hv, lv;
    #pragma unroll
    for (int j = 0; j < 8; ++j) {
      s2 = fmaf(xs[j], xs[j], s2);
      unsigned short h = bf16hi(xs[j]);
      hv[j] = (short)h;
      lv[j] = (short)bf16hi(xs[j] - bf16tof(h));
    }
    *(short8v*)(dh + g * 8) = hv;
    *(short8v*)(dl + g * 8) = lv;
  }
  s2 += __shfl_xor(s2, 1); s2 += __shfl_xor(s2, 2); s2 += __shfl_xor(s2, 4);
  if (sub == 0) se2[row] = s2;
}

// ---------------- fused MFMA distance + softmax + argmin + gather + MSE ----------------
__global__ __launch_bounds__(512, 1) void kMain(
    const float* __restrict__ audio, const float* __restrict__ eeg,
    const float* __restrict__ emb, float* out, float* __restrict__ ws) {
  __shared__ unsigned short Xh[64 * 128];   // K-half staging, swizzled
  __shared__ unsigned short Xl[64 * 128];
  __shared__ float se2l[Mn];
  __shared__ float sx2l[64];
  __shared__ float wmin[64][8];
  __shared__ int   widx[64][8];
  __shared__ float wZ[64][8];
  __shared__ float rowLs[64];
  __shared__ int   rowIdxs[64];
  __shared__ float izs[64];
  __shared__ float redm[8][4];

  const int tid = threadIdx.x;
  const int n0 = blockIdx.x * 32;
  const int b = blockIdx.x >> 4;            // n0 / 512
  const unsigned short* Eh = (const unsigned short*)(ws + OFF_EH);
  const unsigned short* El = (const unsigned short*)(ws + OFF_EL);

  const int lane = tid & 63, wid = tid >> 6;
  const int c = lane & 15, g = lane >> 4;
  const int colbase = wid * 128;

  // se2 -> LDS
  se2l[tid] = ws[OFF_SE2 + tid];
  se2l[tid + 512] = ws[OFF_SE2 + tid + 512];

  float4v acc[4][8];
  #pragma unroll
  for (int rg = 0; rg < 4; ++rg)
    #pragma unroll
    for (int cg = 0; cg < 8; ++cg) {
      float4v z = {0.f, 0.f, 0.f, 0.f};
      acc[rg][cg] = z;
    }

  // per-lane addressing
  const int srow = tid >> 3, ssub = tid & 7;           // staging role
  const float* ssrc = (srow < 32) ? (audio + (size_t)(n0 + srow) * Dn)
                                  : (eeg + (size_t)(n0 + srow - 32) * Dn);
  const int sswz = (srow & 7) << 4;
  char* XhB = (char*)Xh;
  char* XlB = (char*)Xl;
  int rowb[4], swzr[4];
  #pragma unroll
  for (int rg = 0; rg < 4; ++rg) {
    int row = rg * 16 + c;
    rowb[rg] = row * 256;                              // byte stride 256 ([64][128] bf16)
    swzr[rg] = (row & 7) << 4;
  }
  int eoff[8];
  #pragma unroll
  for (int cg = 0; cg < 8; ++cg)
    eoff[cg] = (colbase + cg * 16 + c) * 256 + g * 8;  // ushort units

  float s2 = 0.f;
  for (int ph = 0; ph < 2; ++ph) {
    if (ph) __syncthreads();                           // K-loop(ph0) done before restage
    // stage 64 rows x 128 dims (this K-half) as hi/lo bf16, swizzled
    {
      const int d0 = ssub * 16;
      const float* sp = ssrc + ph * 128 + d0;
      #pragma unroll
      for (int g2 = 0; g2 < 2; ++g2) {
        float4 v0 = ((const float4*)sp)[g2 * 2];
        float4 v1 = ((const float4*)sp)[g2 * 2 + 1];
        float xs[8] = {v0.x, v0.y, v0.z, v0.w, v1.x, v1.y, v1.z, v1.w};
        short8v hv, lv;
        #pragma unroll
        for (int j = 0; j < 8; ++j) {
          s2 = fmaf(xs[j], xs[j], s2);
          unsigned short h = bf16hi(xs[j]);
          hv[j] = (short)h;
          lv[j] = (short)bf16hi(xs[j] - bf16tof(h));
        }
        const int ab = (srow * 256 + (d0 + g2 * 8) * 2) ^ sswz;
        *(short8v*)(XhB + ab) = hv;
        *(short8v*)(XlB + ab) = lv;
      }
    }
    __syncthreads();
    // K-loop over this half: 4 steps of K=32
    for (int ks4 = 0; ks4 < 4; ++ks4) {
      const int kb = ks4 * 64 + g * 16;                // byte offset in row
      const int kg = ph * 128 + ks4 * 32;              // global k (ushort units)
      short8v ah[4], al[4];
      #pragma unroll
      for (int rg = 0; rg < 4; ++rg) {
        const int ab = rowb[rg] + (kb ^ swzr[rg]);
        ah[rg] = *(const short8v*)(XhB + ab);
        al[rg] = *(const short8v*)(XlB + ab);
      }
      #pragma unroll
      for (int cg = 0; cg < 8; ++cg) {
        short8v bh = *(const short8v*)(Eh + eoff[cg] + kg);
        short8v bl = *(const short8v*)(El + eoff[cg] + kg);
        #pragma unroll
        for (int rg = 0; rg < 4; ++rg) {
          acc[rg][cg] = __builtin_amdgcn_mfma_f32_16x16x32_bf16(ah[rg], bh, acc[rg][cg], 0, 0, 0);
          acc[rg][cg] = __builtin_amdgcn_mfma_f32_16x16x32_bf16(al[rg], bh, acc[rg][cg], 0, 0, 0);
          acc[rg][cg] = __builtin_amdgcn_mfma_f32_16x16x32_bf16(ah[rg], bl, acc[rg][cg], 0, 0, 0);
        }
      }
    }
  }
  // sx2 per row
  s2 += __shfl_xor(s2, 1); s2 += __shfl_xor(s2, 2); s2 += __shfl_xor(s2, 4);
  if (ssub == 0) sx2l[srow] = s2;

  // ---- part[m] = se2[m] - 2*dot, in place ----
  float se2c[8];
  #pragma unroll
  for (int cg = 0; cg < 8; ++cg) se2c[cg] = se2l[colbase + cg * 16 + c];
  #pragma unroll
  for (int rg = 0; rg < 4; ++rg)
    #pragma unroll
    for (int cg = 0; cg < 8; ++cg)
      #pragma unroll
      for (int q = 0; q < 4; ++q)
        acc[rg][cg][q] = fmaf(-2.f, acc[rg][cg][q], se2c[cg]);

  // ---- P1: per-row min/argmin ----
  float vmin[4][4]; int imin[4][4];
  #pragma unroll
  for (int rg = 0; rg < 4; ++rg)
    #pragma unroll
    for (int q = 0; q < 4; ++q) { vmin[rg][q] = 3.0e38f; imin[rg][q] = Mn; }
  #pragma unroll
  for (int cg = 0; cg < 8; ++cg) {
    const int colc = colbase + cg * 16 + c;
    #pragma unroll
    for (int rg = 0; rg < 4; ++rg)
      #pragma unroll
      for (int q = 0; q < 4; ++q) {
        float v = acc[rg][cg][q];
        if (v < vmin[rg][q]) { vmin[rg][q] = v; imin[rg][q] = colc; }
      }
  }
  #pragma unroll
  for (int off = 1; off <= 8; off <<= 1) {
    #pragma unroll
    for (int rg = 0; rg < 4; ++rg)
      #pragma unroll
      for (int q = 0; q < 4; ++q) {
        float ov = __shfl_xor(vmin[rg][q], off);
        int oi = __shfl_xor(imin[rg][q], off);
        if (ov < vmin[rg][q] || (ov == vmin[rg][q] && oi < imin[rg][q])) {
          vmin[rg][q] = ov; imin[rg][q] = oi;
        }
      }
  }
  if (c == 0) {
    #pragma unroll
    for (int rg = 0; rg < 4; ++rg)
      #pragma unroll
      for (int q = 0; q < 4; ++q) {
        int row = rg * 16 + g * 4 + q;
        wmin[row][wid] = vmin[rg][q];
        widx[row][wid] = imin[rg][q];
      }
  }
  __syncthreads();
  if (tid < 64) {
    float m = wmin[tid][0]; int mi = widx[tid][0];
    #pragma unroll
    for (int w = 1; w < 8; ++w) {
      float v = wmin[tid][w]; int i2 = widx[tid][w];
      if (v < m || (v == m && i2 < mi)) { m = v; mi = i2; }
    }
    rowIdxs[tid] = mi;
    rowLs[tid] = sqrtf(fmaxf(m + sx2l[tid], 0.f));
  }
  __syncthreads();
  // counts
  if (tid < 32) atomicAdd((unsigned*)(ws + OFF_ACNT) + b * Mn + rowIdxs[tid], 1u);
  else if (tid < 64) atomicAdd((unsigned*)(ws + OFF_ECNT) + b * Mn + rowIdxs[tid], 1u);

  // ---- P2: p = exp(L - sqrt(d)), Z ----
  float Lpre[4][4], spre[4][4];
  #pragma unroll
  for (int rg = 0; rg < 4; ++rg)
    #pragma unroll
    for (int q = 0; q < 4; ++q) {
      int row = rg * 16 + g * 4 + q;
      Lpre[rg][q] = rowLs[row];
      spre[rg][q] = sx2l[row];
    }
  float zp[4][4];
  #pragma unroll
  for (int rg = 0; rg < 4; ++rg)
    #pragma unroll
    for (int q = 0; q < 4; ++q) zp[rg][q] = 0.f;
  #pragma unroll
  for (int rg = 0; rg < 4; ++rg)
    #pragma unroll
    for (int cg = 0; cg < 8; ++cg)
      #pragma unroll
      for (int q = 0; q < 4; ++q) {
        float d = acc[rg][cg][q] + spre[rg][q];
        float pv = __expf(Lpre[rg][q] - sqrtf(fmaxf(d, 0.f)));
        acc[rg][cg][q] = pv;
        zp[rg][q] += pv;
      }
  #pragma unroll
  for (int off = 1; off <= 8; off <<= 1)
    #pragma unroll
    for (int rg = 0; rg < 4; ++rg)
      #pragma unroll
      for (int q = 0; q < 4; ++q) zp[rg][q] += __shfl_xor(zp[rg][q], off);
  if (c == 0) {
    #pragma unroll
    for (int rg = 0; rg < 4; ++rg)
      #pragma unroll
      for (int q = 0; q < 4; ++q) wZ[rg * 16 + g * 4 + q][wid] = zp[rg][q];
  }
  __syncthreads();
  if (tid < 64) {
    float Z = 0.f;
    #pragma unroll
    for (int w = 0; w < 8; ++w) Z += wZ[tid][w];
    izs[tid] = 1.f / Z;
  }
  __syncthreads();

  // ---- P3: probability accumulation into ph[b][m] ----
  float izq[4][4];
  #pragma unroll
  for (int rg = 0; rg < 4; ++rg)
    #pragma unroll
    for (int q = 0; q < 4; ++q) izq[rg][q] = izs[rg * 16 + g * 4 + q];
  float psA[8], psE[8];
  #pragma unroll
  for (int cg = 0; cg < 8; ++cg) {
    float a = 0.f, e = 0.f;
    #pragma unroll
    for (int q = 0; q < 4; ++q) {
      a += acc[0][cg][q] * izq[0][q] + acc[1][cg][q] * izq[1][q];
      e += acc[2][cg][q] * izq[2][q] + acc[3][cg][q] * izq[3][q];
    }
    a += __shfl_xor(a, 16); a += __shfl_xor(a, 32);
    e += __shfl_xor(e, 16); e += __shfl_xor(e, 32);
    psA[cg] = a; psE[cg] = e;
  }
  if (lane < 16) {
    float* phA = ws + OFF_APH;
    float* phE = ws + OFF_EPH;
    #pragma unroll
    for (int cg = 0; cg < 8; ++cg) {
      int colc = colbase + cg * 16 + lane;
      atomicAdd(phA + b * Mn + colc, psA[cg]);
      atomicAdd(phE + b * Mn + colc, psE[cg]);
    }
  }

  // ---- P5: gather quantized rows + commitment MSE partials ----
  {
    const int r = tid >> 4, pp = tid & 15;
    const int ia = rowIdxs[r], ie = rowIdxs[32 + r];
    const float4* qa = (const float4*)(emb + (size_t)ia * Dn);
    const float4* qe = (const float4*)(emb + (size_t)ie * Dn);
    const float4* xa4 = (const float4*)(audio + (size_t)(n0 + r) * Dn);
    const float4* xe4 = (const float4*)(eeg + (size_t)(n0 + r) * Dn);
    float4* oA = (float4*)(out + (size_t)(n0 + r) * Dn);
    float4* oE = (float4*)(out + NnDn + (size_t)(n0 + r) * Dn);
    float s_ae = 0.f, s_aq = 0.f, s_ee = 0.f, s_eq = 0.f;
    #pragma unroll
    for (int h = 0; h < 4; ++h) {
      const int i4 = pp * 4 + h;
      float4 qav = qa[i4], qev = qe[i4], xav = xa4[i4], xev = xe4[i4];
      float qaf[4] = {qav.x, qav.y, qav.z, qav.w};
      float qef[4] = {qev.x, qev.y, qev.z, qev.w};
      float xaf[4] = {xav.x, xav.y, xav.z, xav.w};
      float xef[4] = {xev.x, xev.y, xev.z, xev.w};
      #pragma unroll
      for (int j = 0; j < 4; ++j) {
        float d1 = xaf[j] - qaf[j]; s_ae += d1 * d1;
        float d2 = xaf[j] - qef[j]; s_aq += d2 * d2;
        float d3 = xef[j] - qef[j]; s_ee += d3 * d3;
        float d4 = xef[j] - qaf[j]; s_eq += d4 * d4;
      }
      oA[i4] = qav;
      oE[i4] = qev;
    }
    #pragma unroll
    for (int off = 1; off <= 32; off <<= 1) {
      s_ae += __shfl_xor(s_ae, off);
      s_aq += __shfl_xor(s_aq, off);
      s_ee += __shfl_xor(s_ee, off);
      s_eq += __shfl_xor(s_eq, off);
    }
    if (lane == 0) {
      redm[wid][0] = s_ae; redm[wid][1] = s_aq;
      redm[wid][2] = s_ee; redm[wid][3] = s_eq;
    }
    __syncthreads();
    if (tid < 4) {
      float t = 0.f;
      #pragma unroll
      for (int w = 0; w < 8; ++w) t += redm[w][tid];
      atomicAdd(ws + OFF_LAT + tid, t);
    }
  }
}

// ---------------- normalize ph + log tables ----------------
__global__ __launch_bounds__(256) void kC0(float* __restrict__ ws) {
  int i = blockIdx.x * 256 + threadIdx.x;
  float a = ws[OFF_APH + i] * (1.f / 512.f);
  float e = ws[OFF_EPH + i] * (1.f / 512.f);
  ws[OFF_APHN + i] = a;
  ws[OFF_EPHN + i] = e;
  ws[OFF_LA + i] = logf(a + 1e-10f);
  ws[OFF_LE + i] = logf(e + 1e-10f);
}

// ---------------- Scode ----------------
__global__ __launch_bounds__(256) void kC1(float* __restrict__ ws) {
  const int i = blockIdx.x;
  const int tid = threadIdx.x;
  const int j = tid >> 2, q = tid & 3;
  const float* ai  = ws + OFF_APHN + (size_t)i * Mn;
  const float* ei  = ws + OFF_EPHN + (size_t)i * Mn;
  const float* lej = ws + OFF_LE + (size_t)j * Mn;
  const float* laj = ws + OFF_LA + (size_t)j * Mn;
  float s = 0.f;
  for (int m = q * 256; m < (q + 1) * 256; ++m)
    s += ai[m] * lej[m] + ei[m] * laj[m];
  s += __shfl_xor(s, 1);
  s += __shfl_xor(s, 2);
  if (q == 0) ws[OFF_SCODE + i * 64 + j] = s;
}

// ---------------- finalize ----------------
__global__ __launch_bounds__(256) void kC2(float* __restrict__ ws, float* __restrict__ out) {
  __shared__ float sc[4096];
  __shared__ float red[256];
  __shared__ float rterm[64];
  __shared__ float maxv;
  const int tid = threadIdx.x;
  const float* scode = ws + OFF_SCODE;
  for (int i = tid; i < 4096; i += 256) sc[i] = scode[i];
  __syncthreads();

  float mx = -3.0e38f;
  for (int i = tid; i < 4096; i += 256) mx = fmaxf(mx, -sc[i]);
  red[tid] = mx; __syncthreads();
  for (int s = 128; s > 0; s >>= 1) {
    if (tid < s) red[tid] = fmaxf(red[tid], red[tid + s]);
    __syncthreads();
  }
  if (tid == 0) maxv = red[0];
  __syncthreads();
  const float Max = maxv;

  if (tid < 64) {
    float rs = 0.f;
    for (int j = 0; j < 64; ++j) rs += expf(sc[tid * 64 + j] + Max);
    float dg = expf(sc[tid * 64 + tid] + Max);
    rterm[tid] = logf(dg / (rs + 1e-5f));
  }
  __syncthreads();
  if (tid == 0) {
    float s = 0.f;
    for (int i = 0; i < 64; ++i) s += rterm[i];
    out[OUT_SCALARS + 4] = -0.5f * s / 64.f;
  }
  if (tid == 1) {
    const float* lat = ws + OFF_LAT;
    const float inv = 1.f / 8388608.f;
    float a_e = lat[0] * inv, ae = lat[1] * inv, e_e = lat[2] * inv, ea = lat[3] * inv;
    out[OUT_SCALARS + 0] = 0.25f * (2.f * a_e + ae);
    out[OUT_SCALARS + 1] = 0.25f * (2.f * e_e + ea);
  }

  const unsigned* acnt = (const unsigned*)(ws + OFF_ACNT);
  const unsigned* ecnt = (const unsigned*)(ws + OFF_ECNT);
  float enta = 0.f, ente = 0.f;
  for (int mm = tid; mm < Mn; mm += 256) {
    unsigned ta = 0, te = 0;
    for (int bb = 0; bb < Bn; ++bb) { ta += acnt[bb * Mn + mm]; te += ecnt[bb * Mn + mm]; }
    float av = (float)ta * (1.f / 32768.f);
    float ev = (float)te * (1.f / 32768.f);
    enta += av * logf(av + 1e-10f);
    ente += ev * logf(ev + 1e-10f);
  }
  __syncthreads(); red[tid] = enta; __syncthreads();
  for (int s = 128; s > 0; s >>= 1) { if (tid < s) red[tid] += red[tid + s]; __syncthreads(); }
  if (tid == 0) out[OUT_SCALARS + 2] = expf(-red[0]);
  __syncthreads(); red[tid] = ente; __syncthreads();
  for (int s = 128; s > 0; s >>= 1) { if (tid < s) red[tid] += red[tid + s]; __syncthreads(); }
  if (tid == 0) out[OUT_SCALARS + 3] = expf(-red[0]);

  // per-sample modes: 64 rows x 4 quarter-threads
  {
    int row = tid >> 2, qq = tid & 3;
    unsigned bA = 0; int ia = qq * 256;
    unsigned bE = 0; int ie = qq * 256;
    for (int m = qq * 256; m < qq * 256 + 256; ++m) {
      unsigned ca = acnt[row * Mn + m]; if (ca > bA) { bA = ca; ia = m; }
      unsigned ce = ecnt[row * Mn + m]; if (ce > bE) { bE = ce; ie = m; }
    }
    #pragma unroll
    for (int off = 1; off <= 2; off <<= 1) {
      unsigned ob = (unsigned)__shfl_xor((int)bA, off); int oi = __shfl_xor(ia, off);
      if (ob > bA || (ob == bA && oi < ia)) { bA = ob; ia = oi; }
      unsigned oe = (unsigned)__shfl_xor((int)bE, off); int oj = __shfl_xor(ie, off);
      if (oe > bE || (oe == bE && oj < ie)) { bE = oe; ie = oj; }
    }
    float eq = (qq == 0 && ia == ie) ? 1.f : 0.f;
    __syncthreads(); red[tid] = eq; __syncthreads();
    for (int s = 128; s > 0; s >>= 1) { if (tid < s) red[tid] += red[tid + s]; __syncthreads(); }
    if (tid == 0) out[OUT_SCALARS + 5] = red[0];
  }
}

extern "C" void kernel_launch(void* const* d_in, const int* in_sizes, int n_in,
                              void* d_out, int out_size, void* d_ws, size_t ws_size,
                              hipStream_t stream) {
  const float* audio = (const float*)d_in[0];
  const float* eeg   = (const float*)d_in[1];
  const float* emb   = (const float*)d_in[2];
  float* out = (float*)d_out;
  float* ws  = (float*)d_ws;
  (void)in_sizes; (void)n_in; (void)out_size; (void)ws_size;

  hipMemsetAsync(d_ws, 0, (size_t)ZERO_FLOATS * sizeof(float), stream);
  hipLaunchKernelGGL(kPrepE, dim3(32), dim3(256), 0, stream, emb, ws);
  hipLaunchKernelGGL(kMain, dim3(Nn / 32), dim3(512), 0, stream, audio, eeg, emb, out, ws);
  hipLaunchKernelGGL(kC0, dim3(256), dim3(256), 0, stream, ws);
  hipLaunchKernelGGL(kC1, dim3(64), dim3(256), 0, stream, ws);
  hipLaunchKernelGGL(kC2, dim3(1), dim3(256), 0, stream, ws, out);
}

// Round 3
// 339.509 us; speedup vs baseline: 1.8344x; 1.1868x over previous
//
#include <hip/hip_runtime.h>
#include <math.h>

#define Bn 64
#define Tn 512
#define Dn 256
#define Mn 1024
#define Nn (Bn * Tn)              // 32768
#define NnDn ((size_t)Nn * Dn)

typedef __attribute__((ext_vector_type(8))) short short8v;
typedef __attribute__((ext_vector_type(4))) float float4v;

// ---------------- workspace layout (float offsets) ----------------
#define OFF_APH   0               // [64*1024] f32
#define OFF_EPH   65536           // [64*1024] f32
#define OFF_ACNT  131072          // [64*1024] u32
#define OFF_ECNT  196608          // [64*1024] u32
#define OFF_LAT   262144          // [4] f32
#define OFF_ENT   262148          // [2] f32 entropy accumulators
#define OFF_MODEA 262152          // [64] i32 (int index into ws)
#define OFF_MODEE 262216          // [64] i32
#define ZERO_FLOATS 262656
#define OFF_SE2   262656          // [1024] f32
#define OFF_EH    263680          // fragment-major: [8][1024][4][8] ushort
#define OFF_EL    394752          // same
#define OFF_APHN  525824
#define OFF_EPHN  591360
#define OFF_LA    656896
#define OFF_LE    722432
#define OFF_SCODE 787968
#define OUT_SCALARS ((size_t)2 * Nn * Dn)

__device__ __forceinline__ unsigned short bf16hi(float x) {
  unsigned u = __float_as_uint(x);
  return (unsigned short)((u + 0x7FFFu + ((u >> 16) & 1u)) >> 16);
}
__device__ __forceinline__ float bf16tof(unsigned short h) {
  return __uint_as_float(((unsigned)h) << 16);
}

// ---------------- prep: embedding -> fragment-major bf16 hi/lo + ||e||^2 ----------------
// EF index = k32*32768 + m*32 + (k%32)  so a wave's (c,g) lanes read contiguous 1KB.
__global__ __launch_bounds__(256) void kPrepE(const float* __restrict__ emb,
                                              float* __restrict__ ws) {
  unsigned short* Eh = (unsigned short*)(ws + OFF_EH);
  unsigned short* El = (unsigned short*)(ws + OFF_EL);
  float* se2 = ws + OFF_SE2;
  const int tid = threadIdx.x;
  const int m = blockIdx.x * 32 + (tid >> 3);
  const int sub = tid & 7;                      // which K=32 chunk
  const float* src = emb + (size_t)m * Dn + sub * 32;
  unsigned short* dh = Eh + (size_t)sub * 32768 + m * 32;
  unsigned short* dl = El + (size_t)sub * 32768 + m * 32;
  float s2 = 0.f;
  #pragma unroll
  for (int gq = 0; gq < 4; ++gq) {
    float4 v0 = ((const float4*)src)[gq * 2];
    float4 v1 = ((const float4*)src)[gq * 2 + 1];
    float xs[8] = {v0.x, v0.y, v0.z, v0.w, v1.x, v1.y, v1.z, v1.w};
    short8v hv, lv;
    #pragma unroll
    for (int j = 0; j < 8; ++j) {
      s2 = fmaf(xs[j], xs[j], s2);
      unsigned short h = bf16hi(xs[j]);
      hv[j] = (short)h;
      lv[j] = (short)bf16hi(xs[j] - bf16tof(h));
    }
    *(short8v*)(dh + gq * 8) = hv;
    *(short8v*)(dl + gq * 8) = lv;
  }
  s2 += __shfl_xor(s2, 1); s2 += __shfl_xor(s2, 2); s2 += __shfl_xor(s2, 4);
  if (sub == 0) se2[m] = s2;
}

// ---------------- fused MFMA distance + softmax + argmin + gather + MSE ----------------
__global__ __launch_bounds__(512, 2) void kMain(
    const float* __restrict__ audio, const float* __restrict__ eeg,
    const float* __restrict__ emb, float* out, float* __restrict__ ws) {
  __shared__ unsigned short Xh[64 * 128];   // K-half staging, swizzled
  __shared__ unsigned short Xl[64 * 128];
  __shared__ float se2l[Mn];
  __shared__ float sx2l[64];
  __shared__ float wmin[64][8];
  __shared__ int   widx[64][8];
  __shared__ float wZ[64][8];
  __shared__ float rowLs[64];
  __shared__ int   rowIdxs[64];
  __shared__ float izs[64];
  __shared__ float redm[8][4];

  const int tid = threadIdx.x;
  const int n0 = blockIdx.x * 32;
  const int b = blockIdx.x >> 4;            // n0 / 512
  const unsigned short* __restrict__ Eh = (const unsigned short*)(ws + OFF_EH);
  const unsigned short* __restrict__ El = (const unsigned short*)(ws + OFF_EL);

  const int lane = tid & 63, wid = tid >> 6;
  const int c = lane & 15, g = lane >> 4;
  const int colbase = wid * 128;

  // se2 -> LDS
  se2l[tid] = ws[OFF_SE2 + tid];
  se2l[tid + 512] = ws[OFF_SE2 + tid + 512];

  float4v acc[4][8];
  #pragma unroll
  for (int rg = 0; rg < 4; ++rg)
    #pragma unroll
    for (int cg = 0; cg < 8; ++cg) {
      float4v z = {0.f, 0.f, 0.f, 0.f};
      acc[rg][cg] = z;
    }

  // per-lane addressing
  const int srow = tid >> 3, ssub = tid & 7;           // staging role
  const float* ssrc = (srow < 32) ? (audio + (size_t)(n0 + srow) * Dn)
                                  : (eeg + (size_t)(n0 + srow - 32) * Dn);
  const int sswz = (srow & 7) << 4;
  char* XhB = (char*)Xh;
  char* XlB = (char*)Xl;
  int rowb[4], swzr[4];
  #pragma unroll
  for (int rg = 0; rg < 4; ++rg) {
    int row = rg * 16 + c;
    rowb[rg] = row * 256;                              // byte stride 256 ([64][128] bf16)
    swzr[rg] = (row & 7) << 4;
  }
  const int eoffv = c * 32 + g * 8;                    // ushort units within 1KB frag

  float s2 = 0.f;
  for (int ph = 0; ph < 2; ++ph) {
    if (ph) __syncthreads();                           // K-loop(ph0) done before restage
    // stage 64 rows x 128 dims (this K-half) as hi/lo bf16, swizzled
    {
      const int d0 = ssub * 16;
      const float* sp = ssrc + ph * 128 + d0;
      #pragma unroll
      for (int g2 = 0; g2 < 2; ++g2) {
        float4 v0 = ((const float4*)sp)[g2 * 2];
        float4 v1 = ((const float4*)sp)[g2 * 2 + 1];
        float xs[8] = {v0.x, v0.y, v0.z, v0.w, v1.x, v1.y, v1.z, v1.w};
        short8v hv, lv;
        #pragma unroll
        for (int j = 0; j < 8; ++j) {
          s2 = fmaf(xs[j], xs[j], s2);
          unsigned short h = bf16hi(xs[j]);
          hv[j] = (short)h;
          lv[j] = (short)bf16hi(xs[j] - bf16tof(h));
        }
        const int ab = (srow * 256 + (d0 + g2 * 8) * 2) ^ sswz;
        *(short8v*)(XhB + ab) = hv;
        *(short8v*)(XlB + ab) = lv;
      }
    }
    __syncthreads();
    // K-loop over this half: 4 steps of K=32
    for (int ks4 = 0; ks4 < 4; ++ks4) {
      const int kb = ks4 * 64 + g * 16;                // byte offset in LDS row
      const unsigned short* peh = Eh + (size_t)(ph * 4 + ks4) * 32768
                                     + (size_t)colbase * 32 + eoffv;
      const unsigned short* pel = El + (size_t)(ph * 4 + ks4) * 32768
                                     + (size_t)colbase * 32 + eoffv;
      short8v ah[4], al[4];
      #pragma unroll
      for (int rg = 0; rg < 4; ++rg) {
        const int ab = rowb[rg] + (kb ^ swzr[rg]);
        ah[rg] = *(const short8v*)(XhB + ab);
        al[rg] = *(const short8v*)(XlB + ab);
      }
      #pragma unroll
      for (int cg = 0; cg < 8; ++cg) {
        short8v bh = *(const short8v*)(peh + cg * 512);   // contiguous 1KB per wave
        short8v bl = *(const short8v*)(pel + cg * 512);
        #pragma unroll
        for (int rg = 0; rg < 4; ++rg) {
          acc[rg][cg] = __builtin_amdgcn_mfma_f32_16x16x32_bf16(ah[rg], bh, acc[rg][cg], 0, 0, 0);
          acc[rg][cg] = __builtin_amdgcn_mfma_f32_16x16x32_bf16(al[rg], bh, acc[rg][cg], 0, 0, 0);
          acc[rg][cg] = __builtin_amdgcn_mfma_f32_16x16x32_bf16(ah[rg], bl, acc[rg][cg], 0, 0, 0);
        }
      }
    }
  }
  // sx2 per row
  s2 += __shfl_xor(s2, 1); s2 += __shfl_xor(s2, 2); s2 += __shfl_xor(s2, 4);
  if (ssub == 0) sx2l[srow] = s2;

  // ---- part[m] = se2[m] - 2*dot, in place ----
  float se2c[8];
  #pragma unroll
  for (int cg = 0; cg < 8; ++cg) se2c[cg] = se2l[colbase + cg * 16 + c];
  #pragma unroll
  for (int rg = 0; rg < 4; ++rg)
    #pragma unroll
    for (int cg = 0; cg < 8; ++cg)
      #pragma unroll
      for (int q = 0; q < 4; ++q)
        acc[rg][cg][q] = fmaf(-2.f, acc[rg][cg][q], se2c[cg]);

  // ---- P1: per-row min/argmin ----
  float vmin[4][4]; int imin[4][4];
  #pragma unroll
  for (int rg = 0; rg < 4; ++rg)
    #pragma unroll
    for (int q = 0; q < 4; ++q) { vmin[rg][q] = 3.0e38f; imin[rg][q] = Mn; }
  #pragma unroll
  for (int cg = 0; cg < 8; ++cg) {
    const int colc = colbase + cg * 16 + c;
    #pragma unroll
    for (int rg = 0; rg < 4; ++rg)
      #pragma unroll
      for (int q = 0; q < 4; ++q) {
        float v = acc[rg][cg][q];
        if (v < vmin[rg][q]) { vmin[rg][q] = v; imin[rg][q] = colc; }
      }
  }
  #pragma unroll
  for (int off = 1; off <= 8; off <<= 1) {
    #pragma unroll
    for (int rg = 0; rg < 4; ++rg)
      #pragma unroll
      for (int q = 0; q < 4; ++q) {
        float ov = __shfl_xor(vmin[rg][q], off);
        int oi = __shfl_xor(imin[rg][q], off);
        if (ov < vmin[rg][q] || (ov == vmin[rg][q] && oi < imin[rg][q])) {
          vmin[rg][q] = ov; imin[rg][q] = oi;
        }
      }
  }
  if (c == 0) {
    #pragma unroll
    for (int rg = 0; rg < 4; ++rg)
      #pragma unroll
      for (int q = 0; q < 4; ++q) {
        int row = rg * 16 + g * 4 + q;
        wmin[row][wid] = vmin[rg][q];
        widx[row][wid] = imin[rg][q];
      }
  }
  __syncthreads();
  if (tid < 64) {
    float m = wmin[tid][0]; int mi = widx[tid][0];
    #pragma unroll
    for (int w = 1; w < 8; ++w) {
      float v = wmin[tid][w]; int i2 = widx[tid][w];
      if (v < m || (v == m && i2 < mi)) { m = v; mi = i2; }
    }
    rowIdxs[tid] = mi;
    rowLs[tid] = sqrtf(fmaxf(m + sx2l[tid], 0.f));
  }
  __syncthreads();
  // counts
  if (tid < 32) atomicAdd((unsigned*)(ws + OFF_ACNT) + b * Mn + rowIdxs[tid], 1u);
  else if (tid < 64) atomicAdd((unsigned*)(ws + OFF_ECNT) + b * Mn + rowIdxs[tid], 1u);

  // ---- P2: p = exp(L - sqrt(d)), Z ----
  float Lpre[4][4], spre[4][4];
  #pragma unroll
  for (int rg = 0; rg < 4; ++rg)
    #pragma unroll
    for (int q = 0; q < 4; ++q) {
      int row = rg * 16 + g * 4 + q;
      Lpre[rg][q] = rowLs[row];
      spre[rg][q] = sx2l[row];
    }
  float zp[4][4];
  #pragma unroll
  for (int rg = 0; rg < 4; ++rg)
    #pragma unroll
    for (int q = 0; q < 4; ++q) zp[rg][q] = 0.f;
  #pragma unroll
  for (int rg = 0; rg < 4; ++rg)
    #pragma unroll
    for (int cg = 0; cg < 8; ++cg)
      #pragma unroll
      for (int q = 0; q < 4; ++q) {
        float d = acc[rg][cg][q] + spre[rg][q];
        float pv = __expf(Lpre[rg][q] - sqrtf(fmaxf(d, 0.f)));
        acc[rg][cg][q] = pv;
        zp[rg][q] += pv;
      }
  #pragma unroll
  for (int off = 1; off <= 8; off <<= 1)
    #pragma unroll
    for (int rg = 0; rg < 4; ++rg)
      #pragma unroll
      for (int q = 0; q < 4; ++q) zp[rg][q] += __shfl_xor(zp[rg][q], off);
  if (c == 0) {
    #pragma unroll
    for (int rg = 0; rg < 4; ++rg)
      #pragma unroll
      for (int q = 0; q < 4; ++q) wZ[rg * 16 + g * 4 + q][wid] = zp[rg][q];
  }
  __syncthreads();
  if (tid < 64) {
    float Z = 0.f;
    #pragma unroll
    for (int w = 0; w < 8; ++w) Z += wZ[tid][w];
    izs[tid] = 1.f / Z;
  }
  __syncthreads();

  // ---- P3: probability accumulation into ph[b][m] ----
  float izq[4][4];
  #pragma unroll
  for (int rg = 0; rg < 4; ++rg)
    #pragma unroll
    for (int q = 0; q < 4; ++q) izq[rg][q] = izs[rg * 16 + g * 4 + q];
  float psA[8], psE[8];
  #pragma unroll
  for (int cg = 0; cg < 8; ++cg) {
    float a = 0.f, e = 0.f;
    #pragma unroll
    for (int q = 0; q < 4; ++q) {
      a += acc[0][cg][q] * izq[0][q] + acc[1][cg][q] * izq[1][q];
      e += acc[2][cg][q] * izq[2][q] + acc[3][cg][q] * izq[3][q];
    }
    a += __shfl_xor(a, 16); a += __shfl_xor(a, 32);
    e += __shfl_xor(e, 16); e += __shfl_xor(e, 32);
    psA[cg] = a; psE[cg] = e;
  }
  if (lane < 16) {
    float* phA = ws + OFF_APH;
    float* phE = ws + OFF_EPH;
    #pragma unroll
    for (int cg = 0; cg < 8; ++cg) {
      int colc = colbase + cg * 16 + lane;
      atomicAdd(phA + b * Mn + colc, psA[cg]);
      atomicAdd(phE + b * Mn + colc, psE[cg]);
    }
  }

  // ---- P5: gather quantized rows + commitment MSE partials ----
  {
    const int r = tid >> 4, pp = tid & 15;
    const int ia = rowIdxs[r], ie = rowIdxs[32 + r];
    const float4* qa = (const float4*)(emb + (size_t)ia * Dn);
    const float4* qe = (const float4*)(emb + (size_t)ie * Dn);
    const float4* xa4 = (const float4*)(audio + (size_t)(n0 + r) * Dn);
    const float4* xe4 = (const float4*)(eeg + (size_t)(n0 + r) * Dn);
    float4* oA = (float4*)(out + (size_t)(n0 + r) * Dn);
    float4* oE = (float4*)(out + NnDn + (size_t)(n0 + r) * Dn);
    float s_ae = 0.f, s_aq = 0.f, s_ee = 0.f, s_eq = 0.f;
    #pragma unroll
    for (int h = 0; h < 4; ++h) {
      const int i4 = pp * 4 + h;
      float4 qav = qa[i4], qev = qe[i4], xav = xa4[i4], xev = xe4[i4];
      float qaf[4] = {qav.x, qav.y, qav.z, qav.w};
      float qef[4] = {qev.x, qev.y, qev.z, qev.w};
      float xaf[4] = {xav.x, xav.y, xav.z, xav.w};
      float xef[4] = {xev.x, xev.y, xev.z, xev.w};
      #pragma unroll
      for (int j = 0; j < 4; ++j) {
        float d1 = xaf[j] - qaf[j]; s_ae += d1 * d1;
        float d2 = xaf[j] - qef[j]; s_aq += d2 * d2;
        float d3 = xef[j] - qef[j]; s_ee += d3 * d3;
        float d4 = xef[j] - qaf[j]; s_eq += d4 * d4;
      }
      oA[i4] = qav;
      oE[i4] = qev;
    }
    #pragma unroll
    for (int off = 1; off <= 32; off <<= 1) {
      s_ae += __shfl_xor(s_ae, off);
      s_aq += __shfl_xor(s_aq, off);
      s_ee += __shfl_xor(s_ee, off);
      s_eq += __shfl_xor(s_eq, off);
    }
    if (lane == 0) {
      redm[wid][0] = s_ae; redm[wid][1] = s_aq;
      redm[wid][2] = s_ee; redm[wid][3] = s_eq;
    }
    __syncthreads();
    if (tid < 4) {
      float t = 0.f;
      #pragma unroll
      for (int w = 0; w < 8; ++w) t += redm[w][tid];
      atomicAdd(ws + OFF_LAT + tid, t);
    }
  }
}

// ---------------- normalize ph + log tables ----------------
__global__ __launch_bounds__(256) void kC0(float* __restrict__ ws) {
  int i = blockIdx.x * 256 + threadIdx.x;
  float a = ws[OFF_APH + i] * (1.f / 512.f);
  float e = ws[OFF_EPH + i] * (1.f / 512.f);
  ws[OFF_APHN + i] = a;
  ws[OFF_EPHN + i] = e;
  ws[OFF_LA + i] = logf(a + 1e-10f);
  ws[OFF_LE + i] = logf(e + 1e-10f);
}

// ---------------- Scode: 256 blocks (i, j-quarter) ----------------
__global__ __launch_bounds__(256) void kC1(float* __restrict__ ws) {
  const int blk = blockIdx.x;
  const int i = blk >> 2, jq = blk & 3;
  const int t = threadIdx.x;
  const int jj = t >> 4, q = t & 15;
  const int j = jq * 16 + jj;
  const float* ai  = ws + OFF_APHN + (size_t)i * Mn;
  const float* ei  = ws + OFF_EPHN + (size_t)i * Mn;
  const float* lej = ws + OFF_LE + (size_t)j * Mn;
  const float* laj = ws + OFF_LA + (size_t)j * Mn;
  float s = 0.f;
  #pragma unroll 4
  for (int m = q * 64; m < q * 64 + 64; ++m)
    s += ai[m] * lej[m] + ei[m] * laj[m];
  s += __shfl_xor(s, 1); s += __shfl_xor(s, 2);
  s += __shfl_xor(s, 4); s += __shfl_xor(s, 8);
  if (q == 0) ws[OFF_SCODE + i * 64 + j] = s;
}

// ---------------- per-sample modes (64 blocks) ----------------
__global__ __launch_bounds__(256) void kMode(float* __restrict__ ws) {
  const int bb = blockIdx.x;
  const unsigned* acnt = (const unsigned*)(ws + OFF_ACNT) + (size_t)bb * Mn;
  const unsigned* ecnt = (const unsigned*)(ws + OFF_ECNT) + (size_t)bb * Mn;
  __shared__ unsigned rv[256]; __shared__ int ri[256];
  __shared__ unsigned rv2[256]; __shared__ int ri2[256];
  const int t = threadIdx.x;
  unsigned bA = 0; int ia = t;
  unsigned bE = 0; int ie = t;
  #pragma unroll
  for (int m = t; m < Mn; m += 256) {
    unsigned ca = acnt[m]; if (ca > bA) { bA = ca; ia = m; }
    unsigned ce = ecnt[m]; if (ce > bE) { bE = ce; ie = m; }
  }
  rv[t] = bA; ri[t] = ia; rv2[t] = bE; ri2[t] = ie;
  __syncthreads();
  for (int s2 = 128; s2 > 0; s2 >>= 1) {
    if (t < s2) {
      if (rv[t + s2] > rv[t] || (rv[t + s2] == rv[t] && ri[t + s2] < ri[t])) {
        rv[t] = rv[t + s2]; ri[t] = ri[t + s2];
      }
      if (rv2[t + s2] > rv2[t] || (rv2[t + s2] == rv2[t] && ri2[t + s2] < ri2[t])) {
        rv2[t] = rv2[t + s2]; ri2[t] = ri2[t + s2];
      }
    }
    __syncthreads();
  }
  if (t == 0) {
    ((int*)ws)[OFF_MODEA + bb] = ri[0];
    ((int*)ws)[OFF_MODEE + bb] = ri2[0];
  }
}

// ---------------- perplexity entropy sums (8 blocks) ----------------
__global__ __launch_bounds__(128) void kPerp(float* __restrict__ ws) {
  const int t = threadIdx.x;
  const int m = blockIdx.x * 128 + t;
  const unsigned* acnt = (const unsigned*)(ws + OFF_ACNT);
  const unsigned* ecnt = (const unsigned*)(ws + OFF_ECNT);
  unsigned ta = 0, te = 0;
  for (int bb = 0; bb < Bn; ++bb) { ta += acnt[(size_t)bb * Mn + m]; te += ecnt[(size_t)bb * Mn + m]; }
  float av = (float)ta * (1.f / 32768.f);
  float ev = (float)te * (1.f / 32768.f);
  float ea = av * logf(av + 1e-10f);
  float ee = ev * logf(ev + 1e-10f);
  #pragma unroll
  for (int off = 1; off <= 32; off <<= 1) { ea += __shfl_xor(ea, off); ee += __shfl_xor(ee, off); }
  __shared__ float r[2][2];
  const int lane = t & 63, w = t >> 6;
  if (lane == 0) { r[w][0] = ea; r[w][1] = ee; }
  __syncthreads();
  if (t == 0) {
    atomicAdd(ws + OFF_ENT + 0, r[0][0] + r[1][0]);
    atomicAdd(ws + OFF_ENT + 1, r[0][1] + r[1][1]);
  }
}

// ---------------- finalize: cmcm, losses, perplexities, equal_num ----------------
__global__ __launch_bounds__(256) void kFin(float* __restrict__ ws, float* __restrict__ out) {
  __shared__ float sc[4096];
  __shared__ float red[256];
  __shared__ float rterm[64];
  __shared__ float maxv;
  const int tid = threadIdx.x;
  for (int i = tid; i < 4096; i += 256) sc[i] = ws[OFF_SCODE + i];
  __syncthreads();

  float mx = -3.0e38f;
  for (int i = tid; i < 4096; i += 256) mx = fmaxf(mx, -sc[i]);
  red[tid] = mx; __syncthreads();
  for (int s = 128; s > 0; s >>= 1) {
    if (tid < s) red[tid] = fmaxf(red[tid], red[tid + s]);
    __syncthreads();
  }
  if (tid == 0) maxv = red[0];
  __syncthreads();
  const float Max = maxv;

  if (tid < 64) {
    float rs = 0.f;
    for (int j = 0; j < 64; ++j) rs += expf(sc[tid * 64 + j] + Max);
    float dg = expf(sc[tid * 64 + tid] + Max);
    rterm[tid] = logf(dg / (rs + 1e-5f));
  }
  __syncthreads();
  if (tid == 0) {
    float s = 0.f;
    for (int i = 0; i < 64; ++i) s += rterm[i];
    out[OUT_SCALARS + 4] = -0.5f * s / 64.f;
  }
  if (tid == 1) {
    const float* lat = ws + OFF_LAT;
    const float inv = 1.f / 8388608.f;
    float a_e = lat[0] * inv, ae = lat[1] * inv, e_e = lat[2] * inv, ea = lat[3] * inv;
    out[OUT_SCALARS + 0] = 0.25f * (2.f * a_e + ae);
    out[OUT_SCALARS + 1] = 0.25f * (2.f * e_e + ea);
  }
  if (tid == 2) out[OUT_SCALARS + 2] = expf(-ws[OFF_ENT + 0]);
  if (tid == 3) out[OUT_SCALARS + 3] = expf(-ws[OFF_ENT + 1]);
  if (tid == 4) {
    const int* ma = (const int*)ws + OFF_MODEA;
    const int* me = (const int*)ws + OFF_MODEE;
    int eq = 0;
    for (int b2 = 0; b2 < 64; ++b2) eq += (ma[b2] == me[b2]) ? 1 : 0;
    out[OUT_SCALARS + 5] = (float)eq;
  }
}

extern "C" void kernel_launch(void* const* d_in, const int* in_sizes, int n_in,
                              void* d_out, int out_size, void* d_ws, size_t ws_size,
                              hipStream_t stream) {
  const float* audio = (const float*)d_in[0];
  const float* eeg   = (const float*)d_in[1];
  const float* emb   = (const float*)d_in[2];
  float* out = (float*)d_out;
  float* ws  = (float*)d_ws;
  (void)in_sizes; (void)n_in; (void)out_size; (void)ws_size;

  hipMemsetAsync(d_ws, 0, (size_t)ZERO_FLOATS * sizeof(float), stream);
  hipLaunchKernelGGL(kPrepE, dim3(32), dim3(256), 0, stream, emb, ws);
  hipLaunchKernelGGL(kMain, dim3(Nn / 32), dim3(512), 0, stream, audio, eeg, emb, out, ws);
  hipLaunchKernelGGL(kC0, dim3(256), dim3(256), 0, stream, ws);
  hipLaunchKernelGGL(kC1, dim3(256), dim3(256), 0, stream, ws);
  hipLaunchKernelGGL(kMode, dim3(64), dim3(256), 0, stream, ws);
  hipLaunchKernelGGL(kPerp, dim3(8), dim3(128), 0, stream, ws);
  hipLaunchKernelGGL(kFin, dim3(1), dim3(256), 0, stream, ws, out);
}

// Round 5
// 336.255 us; speedup vs baseline: 1.8522x; 1.0097x over previous
//
#include <hip/hip_runtime.h>
#include <math.h>

#define Bn 64
#define Tn 512
#define Dn 256
#define Mn 1024
#define Nn (Bn * Tn)              // 32768
#define NnDn ((size_t)Nn * Dn)

typedef __attribute__((ext_vector_type(8))) short short8v;
typedef __attribute__((ext_vector_type(4))) float float4v;

// ---------------- workspace layout (float offsets) ----------------
#define OFF_APH   0               // [64*1024] f32
#define OFF_EPH   65536           // [64*1024] f32
#define OFF_ACNT  131072          // [64*1024] u32
#define OFF_ECNT  196608          // [64*1024] u32
#define OFF_LAT   262144          // [4] f32
#define OFF_ENT   262148          // [2] f32 entropy accumulators
#define OFF_MODEA 262152          // [64] i32
#define OFF_MODEE 262216          // [64] i32
#define ZERO_FLOATS 262656
#define OFF_SE2   262656          // [1024] f32
#define OFF_EH    263680          // fragment-major: [8][1024][4][8] ushort
#define OFF_EL    394752          // same (El = Eh + 262144 ushorts)
#define OFF_APHN  525824
#define OFF_EPHN  591360
#define OFF_LA    656896
#define OFF_LE    722432
#define OFF_SCODE 787968
#define OUT_SCALARS ((size_t)2 * Nn * Dn)

__device__ __forceinline__ unsigned short bf16hi(float x) {
  unsigned u = __float_as_uint(x);
  return (unsigned short)((u + 0x7FFFu + ((u >> 16) & 1u)) >> 16);
}
__device__ __forceinline__ float bf16tof(unsigned short h) {
  return __uint_as_float(((unsigned)h) << 16);
}

// ---------------- prep: embedding -> fragment-major bf16 hi/lo + ||e||^2 ----------------
__global__ __launch_bounds__(256) void kPrepE(const float* __restrict__ emb,
                                              float* __restrict__ ws) {
  unsigned short* Eh = (unsigned short*)(ws + OFF_EH);
  unsigned short* El = (unsigned short*)(ws + OFF_EL);
  float* se2 = ws + OFF_SE2;
  const int tid = threadIdx.x;
  const int m = blockIdx.x * 32 + (tid >> 3);
  const int sub = tid & 7;                      // which K=32 chunk
  const float* src = emb + (size_t)m * Dn + sub * 32;
  unsigned short* dh = Eh + (size_t)sub * 32768 + m * 32;
  unsigned short* dl = El + (size_t)sub * 32768 + m * 32;
  float s2 = 0.f;
  #pragma unroll
  for (int gq = 0; gq < 4; ++gq) {
    float4 v0 = ((const float4*)src)[gq * 2];
    float4 v1 = ((const float4*)src)[gq * 2 + 1];
    float xs[8] = {v0.x, v0.y, v0.z, v0.w, v1.x, v1.y, v1.z, v1.w};
    short8v hv, lv;
    #pragma unroll
    for (int j = 0; j < 8; ++j) {
      s2 = fmaf(xs[j], xs[j], s2);
      unsigned short h = bf16hi(xs[j]);
      hv[j] = (short)h;
      lv[j] = (short)bf16hi(xs[j] - bf16tof(h));
    }
    *(short8v*)(dh + gq * 8) = hv;
    *(short8v*)(dl + gq * 8) = lv;
  }
  s2 += __shfl_xor(s2, 1); s2 += __shfl_xor(s2, 2); s2 += __shfl_xor(s2, 4);
  if (sub == 0) se2[m] = s2;
}

// ---------------- fused MFMA distance + softmax + argmin + gather + MSE ----------------
// 1024 threads = 16 waves; wave w owns 64 codes (4 x 16-col fragments).
// acc[4][4] = 64 regs/lane -> <=128 total -> 4 waves/SIMD occupancy.
__global__ __launch_bounds__(1024) void kMain(
    const float* __restrict__ audio, const float* __restrict__ eeg,
    const float* __restrict__ emb, float* out, float* __restrict__ ws) {
  __shared__ unsigned short Xh[64 * 128];   // K-half staging, swizzled (16 KB)
  __shared__ unsigned short Xl[64 * 128];
  __shared__ float se2l[Mn];
  __shared__ float sx2l[64];
  __shared__ float wmin[64][16];
  __shared__ int   widx[64][16];
  __shared__ float wZ[64][16];
  __shared__ float rowLs[64];
  __shared__ int   rowIdxs[64];
  __shared__ float izs[64];
  __shared__ float redm[16][4];

  const int tid = threadIdx.x;
  const int n0 = blockIdx.x * 32;
  const int b = blockIdx.x >> 4;            // n0 / 512
  const unsigned short* __restrict__ Eh = (const unsigned short*)(ws + OFF_EH);

  const int lane = tid & 63, wid = tid >> 6;
  const int c = lane & 15, g = lane >> 4;
  const int colbase = wid * 64;

  se2l[tid] = ws[OFF_SE2 + tid];

  float4v acc[4][4];
  #pragma unroll
  for (int rg = 0; rg < 4; ++rg)
    #pragma unroll
    for (int cg = 0; cg < 4; ++cg) {
      float4v z = {0.f, 0.f, 0.f, 0.f};
      acc[rg][cg] = z;
    }

  // staging roles: 64 rows x 16 threads; each thread does 8 dims/phase
  const int srow = tid >> 4, ssub = tid & 15;
  const float* ssrc = (srow < 32) ? (audio + (size_t)(n0 + srow) * Dn)
                                  : (eeg + (size_t)(n0 + srow - 32) * Dn);
  const int sab = (srow * 256 + ssub * 16) ^ ((srow & 7) << 4);
  char* XhB = (char*)Xh;
  char* XlB = (char*)Xl;
  int rowb[4], swzr[4];
  #pragma unroll
  for (int rg = 0; rg < 4; ++rg) {
    int row = rg * 16 + c;
    rowb[rg] = row * 256;                              // byte stride 256
    swzr[rg] = (row & 7) << 4;
  }
  // B-fragment base: wave-contiguous 1KB per cg
  const unsigned short* pEH = Eh + (size_t)colbase * 32 + (c * 32 + g * 8);

  float s2 = 0.f;
  for (int ph = 0; ph < 2; ++ph) {
    if (ph) __syncthreads();
    // stage this K-half
    {
      const float* sp = ssrc + ph * 128 + ssub * 8;
      float4 v0 = ((const float4*)sp)[0];
      float4 v1 = ((const float4*)sp)[1];
      float xs[8] = {v0.x, v0.y, v0.z, v0.w, v1.x, v1.y, v1.z, v1.w};
      short8v hv, lv;
      #pragma unroll
      for (int j = 0; j < 8; ++j) {
        s2 = fmaf(xs[j], xs[j], s2);
        unsigned short h = bf16hi(xs[j]);
        hv[j] = (short)h;
        lv[j] = (short)bf16hi(xs[j] - bf16tof(h));
      }
      *(short8v*)(XhB + sab) = hv;
      *(short8v*)(XlB + sab) = lv;
    }
    __syncthreads();
    for (int ks4 = 0; ks4 < 4; ++ks4) {
      const int kb = ks4 * 64 + g * 16;
      const unsigned short* peh = pEH + (size_t)(ph * 4 + ks4) * 32768;
      short8v ah[4], al[4];
      #pragma unroll
      for (int rg = 0; rg < 4; ++rg) {
        const int ab = rowb[rg] + (kb ^ swzr[rg]);
        ah[rg] = *(const short8v*)(XhB + ab);
        al[rg] = *(const short8v*)(XlB + ab);
      }
      #pragma unroll
      for (int cg = 0; cg < 4; ++cg) {
        short8v bh = *(const short8v*)(peh + cg * 512);
        short8v bl = *(const short8v*)(peh + cg * 512 + 262144);
        #pragma unroll
        for (int rg = 0; rg < 4; ++rg) {
          acc[rg][cg] = __builtin_amdgcn_mfma_f32_16x16x32_bf16(ah[rg], bh, acc[rg][cg], 0, 0, 0);
          acc[rg][cg] = __builtin_amdgcn_mfma_f32_16x16x32_bf16(al[rg], bh, acc[rg][cg], 0, 0, 0);
          acc[rg][cg] = __builtin_amdgcn_mfma_f32_16x16x32_bf16(ah[rg], bl, acc[rg][cg], 0, 0, 0);
        }
      }
    }
  }
  // sx2 per row (16 lanes per row)
  s2 += __shfl_xor(s2, 1); s2 += __shfl_xor(s2, 2);
  s2 += __shfl_xor(s2, 4); s2 += __shfl_xor(s2, 8);
  if (ssub == 0) sx2l[srow] = s2;

  // ---- part[m] = se2[m] - 2*dot ----
  float se2c[4];
  #pragma unroll
  for (int cg = 0; cg < 4; ++cg) se2c[cg] = se2l[colbase + cg * 16 + c];
  #pragma unroll
  for (int rg = 0; rg < 4; ++rg)
    #pragma unroll
    for (int cg = 0; cg < 4; ++cg)
      #pragma unroll
      for (int q = 0; q < 4; ++q)
        acc[rg][cg][q] = fmaf(-2.f, acc[rg][cg][q], se2c[cg]);

  // ---- P1: per-row min/argmin ----
  float vmin[4][4]; int imin[4][4];
  #pragma unroll
  for (int rg = 0; rg < 4; ++rg)
    #pragma unroll
    for (int q = 0; q < 4; ++q) { vmin[rg][q] = 3.0e38f; imin[rg][q] = Mn; }
  #pragma unroll
  for (int cg = 0; cg < 4; ++cg) {
    const int colc = colbase + cg * 16 + c;
    #pragma unroll
    for (int rg = 0; rg < 4; ++rg)
      #pragma unroll
      for (int q = 0; q < 4; ++q) {
        float v = acc[rg][cg][q];
        if (v < vmin[rg][q]) { vmin[rg][q] = v; imin[rg][q] = colc; }
      }
  }
  #pragma unroll
  for (int off = 1; off <= 8; off <<= 1) {
    #pragma unroll
    for (int rg = 0; rg < 4; ++rg)
      #pragma unroll
      for (int q = 0; q < 4; ++q) {
        float ov = __shfl_xor(vmin[rg][q], off);
        int oi = __shfl_xor(imin[rg][q], off);
        if (ov < vmin[rg][q] || (ov == vmin[rg][q] && oi < imin[rg][q])) {
          vmin[rg][q] = ov; imin[rg][q] = oi;
        }
      }
  }
  if (c == 0) {
    #pragma unroll
    for (int rg = 0; rg < 4; ++rg)
      #pragma unroll
      for (int q = 0; q < 4; ++q) {
        int row = rg * 16 + g * 4 + q;
        wmin[row][wid] = vmin[rg][q];
        widx[row][wid] = imin[rg][q];
      }
  }
  __syncthreads();
  if (tid < 64) {
    float m = wmin[tid][0]; int mi = widx[tid][0];
    #pragma unroll
    for (int w = 1; w < 16; ++w) {
      float v = wmin[tid][w]; int i2 = widx[tid][w];
      if (v < m || (v == m && i2 < mi)) { m = v; mi = i2; }
    }
    rowIdxs[tid] = mi;
    rowLs[tid] = sqrtf(fmaxf(m + sx2l[tid], 0.f));
  }
  __syncthreads();
  if (tid < 32) atomicAdd((unsigned*)(ws + OFF_ACNT) + b * Mn + rowIdxs[tid], 1u);
  else if (tid < 64) atomicAdd((unsigned*)(ws + OFF_ECNT) + b * Mn + rowIdxs[tid], 1u);

  // ---- P2: p = exp(L - sqrt(d)), Z ----
  float Lpre[4][4], spre[4][4];
  #pragma unroll
  for (int rg = 0; rg < 4; ++rg)
    #pragma unroll
    for (int q = 0; q < 4; ++q) {
      int row = rg * 16 + g * 4 + q;
      Lpre[rg][q] = rowLs[row];
      spre[rg][q] = sx2l[row];
    }
  float zp[4][4];
  #pragma unroll
  for (int rg = 0; rg < 4; ++rg)
    #pragma unroll
    for (int q = 0; q < 4; ++q) zp[rg][q] = 0.f;
  #pragma unroll
  for (int rg = 0; rg < 4; ++rg)
    #pragma unroll
    for (int cg = 0; cg < 4; ++cg)
      #pragma unroll
      for (int q = 0; q < 4; ++q) {
        float d = acc[rg][cg][q] + spre[rg][q];
        float pv = __expf(Lpre[rg][q] - sqrtf(fmaxf(d, 0.f)));
        acc[rg][cg][q] = pv;
        zp[rg][q] += pv;
      }
  #pragma unroll
  for (int off = 1; off <= 8; off <<= 1)
    #pragma unroll
    for (int rg = 0; rg < 4; ++rg)
      #pragma unroll
      for (int q = 0; q < 4; ++q) zp[rg][q] += __shfl_xor(zp[rg][q], off);
  if (c == 0) {
    #pragma unroll
    for (int rg = 0; rg < 4; ++rg)
      #pragma unroll
      for (int q = 0; q < 4; ++q) wZ[rg * 16 + g * 4 + q][wid] = zp[rg][q];
  }
  __syncthreads();
  if (tid < 64) {
    float Z = 0.f;
    #pragma unroll
    for (int w = 0; w < 16; ++w) Z += wZ[tid][w];
    izs[tid] = 1.f / Z;
  }
  __syncthreads();

  // ---- P3: probability accumulation into ph[b][m] ----
  float izq[4][4];
  #pragma unroll
  for (int rg = 0; rg < 4; ++rg)
    #pragma unroll
    for (int q = 0; q < 4; ++q) izq[rg][q] = izs[rg * 16 + g * 4 + q];
  float psA[4], psE[4];
  #pragma unroll
  for (int cg = 0; cg < 4; ++cg) {
    float a = 0.f, e = 0.f;
    #pragma unroll
    for (int q = 0; q < 4; ++q) {
      a += acc[0][cg][q] * izq[0][q] + acc[1][cg][q] * izq[1][q];
      e += acc[2][cg][q] * izq[2][q] + acc[3][cg][q] * izq[3][q];
    }
    a += __shfl_xor(a, 16); a += __shfl_xor(a, 32);
    e += __shfl_xor(e, 16); e += __shfl_xor(e, 32);
    psA[cg] = a; psE[cg] = e;
  }
  if (lane < 16) {
    float* phA = ws + OFF_APH;
    float* phE = ws + OFF_EPH;
    #pragma unroll
    for (int cg = 0; cg < 4; ++cg) {
      int colc = colbase + cg * 16 + lane;
      atomicAdd(phA + b * Mn + colc, psA[cg]);
      atomicAdd(phE + b * Mn + colc, psE[cg]);
    }
  }

  // ---- P5: gather quantized rows + commitment MSE partials ----
  {
    const int r = tid >> 5, pp = tid & 31;         // 32 rows x 32 threads
    const int ia = rowIdxs[r], ie = rowIdxs[32 + r];
    const float4* qa = (const float4*)(emb + (size_t)ia * Dn);
    const float4* qe = (const float4*)(emb + (size_t)ie * Dn);
    const float4* xa4 = (const float4*)(audio + (size_t)(n0 + r) * Dn);
    const float4* xe4 = (const float4*)(eeg + (size_t)(n0 + r) * Dn);
    float4* oA = (float4*)(out + (size_t)(n0 + r) * Dn);
    float4* oE = (float4*)(out + NnDn + (size_t)(n0 + r) * Dn);
    float s_ae = 0.f, s_aq = 0.f, s_ee = 0.f, s_eq = 0.f;
    #pragma unroll
    for (int h = 0; h < 2; ++h) {
      const int i4 = pp * 2 + h;
      float4 qav = qa[i4], qev = qe[i4], xav = xa4[i4], xev = xe4[i4];
      float qaf[4] = {qav.x, qav.y, qav.z, qav.w};
      float qef[4] = {qev.x, qev.y, qev.z, qev.w};
      float xaf[4] = {xav.x, xav.y, xav.z, xav.w};
      float xef[4] = {xev.x, xev.y, xev.z, xev.w};
      #pragma unroll
      for (int j = 0; j < 4; ++j) {
        float d1 = xaf[j] - qaf[j]; s_ae += d1 * d1;
        float d2 = xaf[j] - qef[j]; s_aq += d2 * d2;
        float d3 = xef[j] - qef[j]; s_ee += d3 * d3;
        float d4 = xef[j] - qaf[j]; s_eq += d4 * d4;
      }
      oA[i4] = qav;
      oE[i4] = qev;
    }
    #pragma unroll
    for (int off = 1; off <= 32; off <<= 1) {
      s_ae += __shfl_xor(s_ae, off);
      s_aq += __shfl_xor(s_aq, off);
      s_ee += __shfl_xor(s_ee, off);
      s_eq += __shfl_xor(s_eq, off);
    }
    if (lane == 0) {
      redm[wid][0] = s_ae; redm[wid][1] = s_aq;
      redm[wid][2] = s_ee; redm[wid][3] = s_eq;
    }
    __syncthreads();
    if (tid < 4) {
      float t = 0.f;
      #pragma unroll
      for (int w = 0; w < 16; ++w) t += redm[w][tid];
      atomicAdd(ws + OFF_LAT + tid, t);
    }
  }
}

// ---------------- fused aux: kC0 (blocks 0-255) | kMode (256-319) | kPerp (320-323) ----------------
__global__ __launch_bounds__(256) void kAux(float* __restrict__ ws) {
  const int blk = blockIdx.x;
  const int t = threadIdx.x;
  if (blk < 256) {
    int i = blk * 256 + t;
    float a = ws[OFF_APH + i] * (1.f / 512.f);
    float e = ws[OFF_EPH + i] * (1.f / 512.f);
    ws[OFF_APHN + i] = a;
    ws[OFF_EPHN + i] = e;
    ws[OFF_LA + i] = logf(a + 1e-10f);
    ws[OFF_LE + i] = logf(e + 1e-10f);
  } else if (blk < 320) {
    const int bb = blk - 256;
    const unsigned* acnt = (const unsigned*)(ws + OFF_ACNT) + (size_t)bb * Mn;
    const unsigned* ecnt = (const unsigned*)(ws + OFF_ECNT) + (size_t)bb * Mn;
    __shared__ unsigned rv[256]; __shared__ int ri[256];
    __shared__ unsigned rv2[256]; __shared__ int ri2[256];
    unsigned bA = 0; int ia = t;
    unsigned bE = 0; int ie = t;
    #pragma unroll
    for (int m = t; m < Mn; m += 256) {
      unsigned ca = acnt[m]; if (ca > bA) { bA = ca; ia = m; }
      unsigned ce = ecnt[m]; if (ce > bE) { bE = ce; ie = m; }
    }
    rv[t] = bA; ri[t] = ia; rv2[t] = bE; ri2[t] = ie;
    __syncthreads();
    for (int s2 = 128; s2 > 0; s2 >>= 1) {
      if (t < s2) {
        if (rv[t + s2] > rv[t] || (rv[t + s2] == rv[t] && ri[t + s2] < ri[t])) {
          rv[t] = rv[t + s2]; ri[t] = ri[t + s2];
        }
        if (rv2[t + s2] > rv2[t] || (rv2[t + s2] == rv2[t] && ri2[t + s2] < ri2[t])) {
          rv2[t] = rv2[t + s2]; ri2[t] = ri2[t + s2];
        }
      }
      __syncthreads();
    }
    if (t == 0) {
      ((int*)ws)[OFF_MODEA + bb] = ri[0];
      ((int*)ws)[OFF_MODEE + bb] = ri2[0];
    }
  } else {
    const int m = (blk - 320) * 256 + t;
    const unsigned* acnt = (const unsigned*)(ws + OFF_ACNT);
    const unsigned* ecnt = (const unsigned*)(ws + OFF_ECNT);
    unsigned ta = 0, te = 0;
    for (int bb = 0; bb < Bn; ++bb) {
      ta += acnt[(size_t)bb * Mn + m];
      te += ecnt[(size_t)bb * Mn + m];
    }
    float av = (float)ta * (1.f / 32768.f);
    float ev = (float)te * (1.f / 32768.f);
    float ea = av * logf(av + 1e-10f);
    float ee = ev * logf(ev + 1e-10f);
    #pragma unroll
    for (int off = 1; off <= 32; off <<= 1) { ea += __shfl_xor(ea, off); ee += __shfl_xor(ee, off); }
    __shared__ float r2[4][2];
    const int ln = t & 63, w = t >> 6;
    if (ln == 0) { r2[w][0] = ea; r2[w][1] = ee; }
    __syncthreads();
    if (t == 0) {
      atomicAdd(ws + OFF_ENT + 0, r2[0][0] + r2[1][0] + r2[2][0] + r2[3][0]);
      atomicAdd(ws + OFF_ENT + 1, r2[0][1] + r2[1][1] + r2[2][1] + r2[3][1]);
    }
  }
}

// ---------------- Scode: 256 blocks (i, j-quarter) ----------------
__global__ __launch_bounds__(256) void kC1(float* __restrict__ ws) {
  const int blk = blockIdx.x;
  const int i = blk >> 2, jq = blk & 3;
  const int t = threadIdx.x;
  const int jj = t >> 4, q = t & 15;
  const int j = jq * 16 + jj;
  const float* ai  = ws + OFF_APHN + (size_t)i * Mn;
  const float* ei  = ws + OFF_EPHN + (size_t)i * Mn;
  const float* lej = ws + OFF_LE + (size_t)j * Mn;
  const float* laj = ws + OFF_LA + (size_t)j * Mn;
  float s = 0.f;
  #pragma unroll 4
  for (int m = q * 64; m < q * 64 + 64; ++m)
    s += ai[m] * lej[m] + ei[m] * laj[m];
  s += __shfl_xor(s, 1); s += __shfl_xor(s, 2);
  s += __shfl_xor(s, 4); s += __shfl_xor(s, 8);
  if (q == 0) ws[OFF_SCODE + i * 64 + j] = s;
}

// ---------------- finalize ----------------
__global__ __launch_bounds__(256) void kFin(float* __restrict__ ws, float* __restrict__ out) {
  __shared__ float sc[4096];
  __shared__ float red[256];
  __shared__ float rterm[64];
  __shared__ float maxv;
  const int tid = threadIdx.x;
  for (int i = tid; i < 4096; i += 256) sc[i] = ws[OFF_SCODE + i];
  __syncthreads();

  float mx = -3.0e38f;
  for (int i = tid; i < 4096; i += 256) mx = fmaxf(mx, -sc[i]);
  red[tid] = mx; __syncthreads();
  for (int s = 128; s > 0; s >>= 1) {
    if (tid < s) red[tid] = fmaxf(red[tid], red[tid + s]);
    __syncthreads();
  }
  if (tid == 0) maxv = red[0];
  __syncthreads();
  const float Max = maxv;

  if (tid < 64) {
    float rs = 0.f;
    for (int j = 0; j < 64; ++j) rs += expf(sc[tid * 64 + j] + Max);
    float dg = expf(sc[tid * 64 + tid] + Max);
    rterm[tid] = logf(dg / (rs + 1e-5f));
  }
  __syncthreads();
  if (tid == 0) {
    float s = 0.f;
    for (int i = 0; i < 64; ++i) s += rterm[i];
    out[OUT_SCALARS + 4] = -0.5f * s / 64.f;
  }
  if (tid == 1) {
    const float* lat = ws + OFF_LAT;
    const float inv = 1.f / 8388608.f;
    float a_e = lat[0] * inv, ae = lat[1] * inv, e_e = lat[2] * inv, ea = lat[3] * inv;
    out[OUT_SCALARS + 0] = 0.25f * (2.f * a_e + ae);
    out[OUT_SCALARS + 1] = 0.25f * (2.f * e_e + ea);
  }
  if (tid == 2) out[OUT_SCALARS + 2] = expf(-ws[OFF_ENT + 0]);
  if (tid == 3) out[OUT_SCALARS + 3] = expf(-ws[OFF_ENT + 1]);
  if (tid == 4) {
    const int* ma = (const int*)ws + OFF_MODEA;
    const int* me = (const int*)ws + OFF_MODEE;
    int eq = 0;
    for (int b2 = 0; b2 < 64; ++b2) eq += (ma[b2] == me[b2]) ? 1 : 0;
    out[OUT_SCALARS + 5] = (float)eq;
  }
}

extern "C" void kernel_launch(void* const* d_in, const int* in_sizes, int n_in,
                              void* d_out, int out_size, void* d_ws, size_t ws_size,
                              hipStream_t stream) {
  const float* audio = (const float*)d_in[0];
  const float* eeg   = (const float*)d_in[1];
  const float* emb   = (const float*)d_in[2];
  float* out = (float*)d_out;
  float* ws  = (float*)d_ws;
  (void)in_sizes; (void)n_in; (void)out_size; (void)ws_size;

  hipMemsetAsync(d_ws, 0, (size_t)ZERO_FLOATS * sizeof(float), stream);
  hipLaunchKernelGGL(kPrepE, dim3(32), dim3(256), 0, stream, emb, ws);
  hipLaunchKernelGGL(kMain, dim3(Nn / 32), dim3(1024), 0, stream, audio, eeg, emb, out, ws);
  hipLaunchKernelGGL(kAux, dim3(324), dim3(256), 0, stream, ws);
  hipLaunchKernelGGL(kC1, dim3(256), dim3(256), 0, stream, ws);
  hipLaunchKernelGGL(kFin, dim3(1), dim3(256), 0, stream, ws, out);
}

// Round 7
// 328.635 us; speedup vs baseline: 1.8951x; 1.0232x over previous
//
#include <hip/hip_runtime.h>
#include <math.h>

#define Bn 64
#define Tn 512
#define Dn 256
#define Mn 1024
#define Nn (Bn * Tn)              // 32768
#define NnDn ((size_t)Nn * Dn)

typedef __attribute__((ext_vector_type(8))) short short8v;
typedef __attribute__((ext_vector_type(4))) float float4v;

// ---------------- workspace layout (float offsets) ----------------
#define OFF_APH   0               // [64*1024] f32
#define OFF_EPH   65536           // [64*1024] f32
#define OFF_ACNT  131072          // [64*1024] u32
#define OFF_ECNT  196608          // [64*1024] u32
#define OFF_LAT   262144          // [4] f32
#define OFF_ENT   262148          // [2] f32 entropy accumulators
#define OFF_MODEA 262152          // [64] i32
#define OFF_MODEE 262216          // [64] i32
#define ZERO_FLOATS 262656
#define OFF_SE2   262656          // [1024] f32
#define OFF_EH    263680          // fragment-major: [8][1024][4][8] ushort
#define OFF_EL    394752          // same (El = Eh + 262144 ushorts)
#define OFF_APHN  525824
#define OFF_EPHN  591360
#define OFF_LA    656896
#define OFF_LE    722432
#define OFF_SCODE 787968
#define OUT_SCALARS ((size_t)2 * Nn * Dn)

#define XSTRB 520                 // LDS X row stride in bytes (512 + 8 pad)

__device__ __forceinline__ unsigned short bf16hi(float x) {
  unsigned u = __float_as_uint(x);
  return (unsigned short)((u + 0x7FFFu + ((u >> 16) & 1u)) >> 16);
}
__device__ __forceinline__ float bf16tof(unsigned short h) {
  return __uint_as_float(((unsigned)h) << 16);
}

// ---------------- prep: embedding -> fragment-major bf16 hi/lo + ||e||^2 ----------------
__global__ __launch_bounds__(256) void kPrepE(const float* __restrict__ emb,
                                              float* __restrict__ ws) {
  unsigned short* Eh = (unsigned short*)(ws + OFF_EH);
  unsigned short* El = (unsigned short*)(ws + OFF_EL);
  float* se2 = ws + OFF_SE2;
  const int tid = threadIdx.x;
  const int m = blockIdx.x * 32 + (tid >> 3);
  const int sub = tid & 7;                      // which K=32 chunk
  const float* src = emb + (size_t)m * Dn + sub * 32;
  unsigned short* dh = Eh + (size_t)sub * 32768 + m * 32;
  unsigned short* dl = El + (size_t)sub * 32768 + m * 32;
  float s2 = 0.f;
  #pragma unroll
  for (int gq = 0; gq < 4; ++gq) {
    float4 v0 = ((const float4*)src)[gq * 2];
    float4 v1 = ((const float4*)src)[gq * 2 + 1];
    float xs[8] = {v0.x, v0.y, v0.z, v0.w, v1.x, v1.y, v1.z, v1.w};
    short8v hv, lv;
    #pragma unroll
    for (int j = 0; j < 8; ++j) {
      s2 = fmaf(xs[j], xs[j], s2);
      unsigned short h = bf16hi(xs[j]);
      hv[j] = (short)h;
      lv[j] = (short)bf16hi(xs[j] - bf16tof(h));
    }
    *(short8v*)(dh + gq * 8) = hv;
    *(short8v*)(dl + gq * 8) = lv;
  }
  s2 += __shfl_xor(s2, 1); s2 += __shfl_xor(s2, 2); s2 += __shfl_xor(s2, 4);
  if (sub == 0) se2[m] = s2;
}

// ---------------- fused MFMA distance + softmax + argmin + gather + MSE ----------------
// 512 threads = 8 waves; block covers 32 rows (16 audio + 16 eeg) x 1024 cols.
// wave owns 128 cols: acc[2][8] = 64 AGPR; total regs <=128 -> 2 blocks/CU.
__global__ __launch_bounds__(512, 4) void kMain(
    const float* __restrict__ audio, const float* __restrict__ eeg,
    const float* __restrict__ emb, float* out, float* __restrict__ ws) {
  __shared__ unsigned short Xh[32 * (XSTRB / 2)];   // 16.6 KB, padded rows
  __shared__ unsigned short Xl[32 * (XSTRB / 2)];
  __shared__ float se2l[Mn];
  __shared__ float sx2l[32];
  __shared__ float wmin[32][8];
  __shared__ int   widx[32][8];
  __shared__ float wZ[32][8];
  __shared__ float rowLs[32];
  __shared__ int   rowIdxs[32];
  __shared__ float izs[32];
  __shared__ float redm[8][4];

  const int tid = threadIdx.x;
  const int n0 = blockIdx.x * 16;           // 16 audio rows + 16 eeg rows
  const int b = blockIdx.x >> 5;            // n0 / 512
  const unsigned short* __restrict__ Eh = (const unsigned short*)(ws + OFF_EH);
  const unsigned short* __restrict__ El = (const unsigned short*)(ws + OFF_EL);

  const int lane = tid & 63, wid = tid >> 6;
  const int c = lane & 15, g = lane >> 4;
  const int colbase = wid * 128;

  se2l[tid] = ws[OFF_SE2 + tid];
  se2l[tid + 512] = ws[OFF_SE2 + tid + 512];

  float4v acc[2][8];
  #pragma unroll
  for (int rg = 0; rg < 2; ++rg)
    #pragma unroll
    for (int cg = 0; cg < 8; ++cg) {
      float4v z = {0.f, 0.f, 0.f, 0.f};
      acc[rg][cg] = z;
    }

  char* XhB = (char*)Xh;
  char* XlB = (char*)Xl;

  // ---- one-shot full-K staging: thread = (row srow, dims ssub*16..+15) ----
  const int srow = tid >> 4, ssub = tid & 15;
  {
    const float* sp = (srow < 16) ? (audio + (size_t)(n0 + srow) * Dn + ssub * 16)
                                  : (eeg + (size_t)(n0 + srow - 16) * Dn + ssub * 16);
    float s2 = 0.f;
    const int ab = srow * XSTRB + ssub * 32;   // padded stride: no swizzle needed
    #pragma unroll
    for (int h = 0; h < 2; ++h) {
      float4 v0 = ((const float4*)sp)[h * 2];
      float4 v1 = ((const float4*)sp)[h * 2 + 1];
      float xs[8] = {v0.x, v0.y, v0.z, v0.w, v1.x, v1.y, v1.z, v1.w};
      short8v hv, lv;
      #pragma unroll
      for (int j = 0; j < 8; ++j) {
        float x = xs[j];
        s2 = fmaf(x, x, s2);
        unsigned u = __float_as_uint(x);
        unsigned r = u + 0x7FFFu + ((u >> 16) & 1u);   // rounded hi
        hv[j] = (short)(unsigned short)(r >> 16);
        float lof = x - __uint_as_float(r & 0xFFFF0000u);
        lv[j] = (short)(unsigned short)(__float_as_uint(lof) >> 16);  // truncated lo
      }
      *(short8v*)(XhB + ab + h * 16) = hv;
      *(short8v*)(XlB + ab + h * 16) = lv;
    }
    s2 += __shfl_xor(s2, 1); s2 += __shfl_xor(s2, 2);
    s2 += __shfl_xor(s2, 4); s2 += __shfl_xor(s2, 8);
    if (ssub == 0) sx2l[srow] = s2;
  }
  __syncthreads();

  // ---- K-loop: 8 steps of K=32, no barriers ----
  {
    const int rowb0 = c * XSTRB;              // audio rows 0-15
    const int rowb1 = (16 + c) * XSTRB;       // eeg rows 16-31
    const unsigned short* pEHb = Eh + (size_t)colbase * 32 + (c * 32 + g * 8);
    const unsigned short* pELb = El + (size_t)colbase * 32 + (c * 32 + g * 8);
    #pragma unroll
    for (int ks = 0; ks < 8; ++ks) {
      const int kb = ks * 64 + g * 16;
      short8v a0h = *(const short8v*)(XhB + rowb0 + kb);
      short8v a0l = *(const short8v*)(XlB + rowb0 + kb);
      short8v a1h = *(const short8v*)(XhB + rowb1 + kb);
      short8v a1l = *(const short8v*)(XlB + rowb1 + kb);
      const unsigned short* peh = pEHb + (size_t)ks * 32768;
      const unsigned short* pel = pELb + (size_t)ks * 32768;
      #pragma unroll
      for (int cg = 0; cg < 8; ++cg) {
        short8v bh = *(const short8v*)(peh + cg * 512);
        short8v bl = *(const short8v*)(pel + cg * 512);
        acc[0][cg] = __builtin_amdgcn_mfma_f32_16x16x32_bf16(a0h, bh, acc[0][cg], 0, 0, 0);
        acc[0][cg] = __builtin_amdgcn_mfma_f32_16x16x32_bf16(a0l, bh, acc[0][cg], 0, 0, 0);
        acc[0][cg] = __builtin_amdgcn_mfma_f32_16x16x32_bf16(a0h, bl, acc[0][cg], 0, 0, 0);
        acc[1][cg] = __builtin_amdgcn_mfma_f32_16x16x32_bf16(a1h, bh, acc[1][cg], 0, 0, 0);
        acc[1][cg] = __builtin_amdgcn_mfma_f32_16x16x32_bf16(a1l, bh, acc[1][cg], 0, 0, 0);
        acc[1][cg] = __builtin_amdgcn_mfma_f32_16x16x32_bf16(a1h, bl, acc[1][cg], 0, 0, 0);
      }
    }
  }

  // ---- d = max(se2 - 2*dot + sx2, 0), in place ----
  float spre[2][4];
  #pragma unroll
  for (int rg = 0; rg < 2; ++rg)
    #pragma unroll
    for (int q = 0; q < 4; ++q) spre[rg][q] = sx2l[rg * 16 + g * 4 + q];
  float se2c[8];
  #pragma unroll
  for (int cg = 0; cg < 8; ++cg) se2c[cg] = se2l[colbase + cg * 16 + c];
  #pragma unroll
  for (int rg = 0; rg < 2; ++rg)
    #pragma unroll
    for (int cg = 0; cg < 8; ++cg)
      #pragma unroll
      for (int q = 0; q < 4; ++q)
        acc[rg][cg][q] = fmaxf(fmaf(-2.f, acc[rg][cg][q], se2c[cg]) + spre[rg][q], 0.f);

  // ---- P1: per-row min (value tree) + first-occurrence index ----
  {
    float vmin[2][4];
    #pragma unroll
    for (int rg = 0; rg < 2; ++rg)
      #pragma unroll
      for (int q = 0; q < 4; ++q) {
        float m01 = fminf(acc[rg][0][q], acc[rg][1][q]);
        float m23 = fminf(acc[rg][2][q], acc[rg][3][q]);
        float m45 = fminf(acc[rg][4][q], acc[rg][5][q]);
        float m67 = fminf(acc[rg][6][q], acc[rg][7][q]);
        vmin[rg][q] = fminf(fminf(m01, m23), fminf(m45, m67));
      }
    #pragma unroll
    for (int off = 1; off <= 8; off <<= 1)
      #pragma unroll
      for (int rg = 0; rg < 2; ++rg)
        #pragma unroll
        for (int q = 0; q < 4; ++q)
          vmin[rg][q] = fminf(vmin[rg][q], __shfl_xor(vmin[rg][q], off));
    // index pass: min col where d == vmin (all lanes hold wave-slab min)
    int imin[2][4];
    #pragma unroll
    for (int rg = 0; rg < 2; ++rg)
      #pragma unroll
      for (int q = 0; q < 4; ++q) {
        int il = Mn;
        #pragma unroll
        for (int cg = 0; cg < 8; ++cg) {
          int colc = colbase + cg * 16 + c;
          if (acc[rg][cg][q] == vmin[rg][q]) il = min(il, colc);
        }
        imin[rg][q] = il;
      }
    #pragma unroll
    for (int off = 1; off <= 8; off <<= 1)
      #pragma unroll
      for (int rg = 0; rg < 2; ++rg)
        #pragma unroll
        for (int q = 0; q < 4; ++q)
          imin[rg][q] = min(imin[rg][q], __shfl_xor(imin[rg][q], off));
    if (c == 0) {
      #pragma unroll
      for (int rg = 0; rg < 2; ++rg)
        #pragma unroll
        for (int q = 0; q < 4; ++q) {
          int row = rg * 16 + g * 4 + q;
          wmin[row][wid] = vmin[rg][q];
          widx[row][wid] = imin[rg][q];
        }
    }
  }
  __syncthreads();
  if (tid < 32) {
    float m = wmin[tid][0]; int mi = widx[tid][0];
    #pragma unroll
    for (int w = 1; w < 8; ++w) {
      float v = wmin[tid][w]; int i2 = widx[tid][w];
      if (v < m || (v == m && i2 < mi)) { m = v; mi = i2; }
    }
    rowIdxs[tid] = mi;
    rowLs[tid] = sqrtf(m);               // d already has sx2 folded + clamped
  }
  __syncthreads();
  if (tid < 16) atomicAdd((unsigned*)(ws + OFF_ACNT) + b * Mn + rowIdxs[tid], 1u);
  else if (tid < 32) atomicAdd((unsigned*)(ws + OFF_ECNT) + b * Mn + rowIdxs[tid], 1u);

  // ---- P2: p = exp(L - sqrt(d)), Z ----
  float Lpre[2][4];
  #pragma unroll
  for (int rg = 0; rg < 2; ++rg)
    #pragma unroll
    for (int q = 0; q < 4; ++q) Lpre[rg][q] = rowLs[rg * 16 + g * 4 + q];
  float zp[2][4];
  #pragma unroll
  for (int rg = 0; rg < 2; ++rg)
    #pragma unroll
    for (int q = 0; q < 4; ++q) zp[rg][q] = 0.f;
  #pragma unroll
  for (int rg = 0; rg < 2; ++rg)
    #pragma unroll
    for (int cg = 0; cg < 8; ++cg)
      #pragma unroll
      for (int q = 0; q < 4; ++q) {
        float pv = __expf(Lpre[rg][q] - sqrtf(acc[rg][cg][q]));
        acc[rg][cg][q] = pv;
        zp[rg][q] += pv;
      }
  #pragma unroll
  for (int off = 1; off <= 8; off <<= 1)
    #pragma unroll
    for (int rg = 0; rg < 2; ++rg)
      #pragma unroll
      for (int q = 0; q < 4; ++q) zp[rg][q] += __shfl_xor(zp[rg][q], off);
  if (c == 0) {
    #pragma unroll
    for (int rg = 0; rg < 2; ++rg)
      #pragma unroll
      for (int q = 0; q < 4; ++q) wZ[rg * 16 + g * 4 + q][wid] = zp[rg][q];
  }
  __syncthreads();
  if (tid < 32) {
    float Z = 0.f;
    #pragma unroll
    for (int w = 0; w < 8; ++w) Z += wZ[tid][w];
    izs[tid] = 1.f / Z;
  }
  __syncthreads();

  // ---- P3: probability accumulation into ph[b][m] ----
  {
    float izq[2][4];
    #pragma unroll
    for (int rg = 0; rg < 2; ++rg)
      #pragma unroll
      for (int q = 0; q < 4; ++q) izq[rg][q] = izs[rg * 16 + g * 4 + q];
    #pragma unroll
    for (int cg = 0; cg < 8; ++cg) {
      float a = 0.f, e = 0.f;
      #pragma unroll
      for (int q = 0; q < 4; ++q) {
        a += acc[0][cg][q] * izq[0][q];
        e += acc[1][cg][q] * izq[1][q];
      }
      a += __shfl_xor(a, 16); a += __shfl_xor(a, 32);
      e += __shfl_xor(e, 16); e += __shfl_xor(e, 32);
      if (lane < 16) {
        int colc = colbase + cg * 16 + lane;
        atomicAdd(ws + OFF_APH + b * Mn + colc, a);
        atomicAdd(ws + OFF_EPH + b * Mn + colc, e);
      }
    }
  }

  // ---- P5: gather quantized rows + commitment MSE partials ----
  {
    const int r = tid >> 5, pp = tid & 31;         // 16 rows x 32 threads
    const int ia = rowIdxs[r], ie = rowIdxs[16 + r];
    const float4* qa = (const float4*)(emb + (size_t)ia * Dn);
    const float4* qe = (const float4*)(emb + (size_t)ie * Dn);
    const float4* xa4 = (const float4*)(audio + (size_t)(n0 + r) * Dn);
    const float4* xe4 = (const float4*)(eeg + (size_t)(n0 + r) * Dn);
    float4* oA = (float4*)(out + (size_t)(n0 + r) * Dn);
    float4* oE = (float4*)(out + NnDn + (size_t)(n0 + r) * Dn);
    float s_ae = 0.f, s_aq = 0.f, s_ee = 0.f, s_eq = 0.f;
    #pragma unroll
    for (int h = 0; h < 2; ++h) {
      const int i4 = pp * 2 + h;
      float4 qav = qa[i4], qev = qe[i4], xav = xa4[i4], xev = xe4[i4];
      float qaf[4] = {qav.x, qav.y, qav.z, qav.w};
      float qef[4] = {qev.x, qev.y, qev.z, qev.w};
      float xaf[4] = {xav.x, xav.y, xav.z, xav.w};
      float xef[4] = {xev.x, xev.y, xev.z, xev.w};
      #pragma unroll
      for (int j = 0; j < 4; ++j) {
        float d1 = xaf[j] - qaf[j]; s_ae += d1 * d1;
        float d2 = xaf[j] - qef[j]; s_aq += d2 * d2;
        float d3 = xef[j] - qef[j]; s_ee += d3 * d3;
        float d4 = xef[j] - qaf[j]; s_eq += d4 * d4;
      }
      oA[i4] = qav;
      oE[i4] = qev;
    }
    #pragma unroll
    for (int off = 1; off <= 32; off <<= 1) {
      s_ae += __shfl_xor(s_ae, off);
      s_aq += __shfl_xor(s_aq, off);
      s_ee += __shfl_xor(s_ee, off);
      s_eq += __shfl_xor(s_eq, off);
    }
    if (lane == 0) {
      redm[wid][0] = s_ae; redm[wid][1] = s_aq;
      redm[wid][2] = s_ee; redm[wid][3] = s_eq;
    }
    __syncthreads();
    if (tid < 4) {
      float t = 0.f;
      #pragma unroll
      for (int w = 0; w < 8; ++w) t += redm[w][tid];
      atomicAdd(ws + OFF_LAT + tid, t);
    }
  }
}

// ---------------- fused aux: kC0 (blocks 0-255) | kMode (256-319) | kPerp (320-323) ----------------
__global__ __launch_bounds__(256) void kAux(float* __restrict__ ws) {
  const int blk = blockIdx.x;
  const int t = threadIdx.x;
  if (blk < 256) {
    int i = blk * 256 + t;
    float a = ws[OFF_APH + i] * (1.f / 512.f);
    float e = ws[OFF_EPH + i] * (1.f / 512.f);
    ws[OFF_APHN + i] = a;
    ws[OFF_EPHN + i] = e;
    ws[OFF_LA + i] = logf(a + 1e-10f);
    ws[OFF_LE + i] = logf(e + 1e-10f);
  } else if (blk < 320) {
    const int bb = blk - 256;
    const unsigned* acnt = (const unsigned*)(ws + OFF_ACNT) + (size_t)bb * Mn;
    const unsigned* ecnt = (const unsigned*)(ws + OFF_ECNT) + (size_t)bb * Mn;
    __shared__ unsigned rv[256]; __shared__ int ri[256];
    __shared__ unsigned rv2[256]; __shared__ int ri2[256];
    unsigned bA = 0; int ia = t;
    unsigned bE = 0; int ie = t;
    #pragma unroll
    for (int m = t; m < Mn; m += 256) {
      unsigned ca = acnt[m]; if (ca > bA) { bA = ca; ia = m; }
      unsigned ce = ecnt[m]; if (ce > bE) { bE = ce; ie = m; }
    }
    rv[t] = bA; ri[t] = ia; rv2[t] = bE; ri2[t] = ie;
    __syncthreads();
    for (int s2 = 128; s2 > 0; s2 >>= 1) {
      if (t < s2) {
        if (rv[t + s2] > rv[t] || (rv[t + s2] == rv[t] && ri[t + s2] < ri[t])) {
          rv[t] = rv[t + s2]; ri[t] = ri[t + s2];
        }
        if (rv2[t + s2] > rv2[t] || (rv2[t + s2] == rv2[t] && ri2[t + s2] < ri2[t])) {
          rv2[t] = rv2[t + s2]; ri2[t] = ri2[t + s2];
        }
      }
      __syncthreads();
    }
    if (t == 0) {
      ((int*)ws)[OFF_MODEA + bb] = ri[0];
      ((int*)ws)[OFF_MODEE + bb] = ri2[0];
    }
  } else {
    const int m = (blk - 320) * 256 + t;
    const unsigned* acnt = (const unsigned*)(ws + OFF_ACNT);
    const unsigned* ecnt = (const unsigned*)(ws + OFF_ECNT);
    unsigned ta = 0, te = 0;
    for (int bb = 0; bb < Bn; ++bb) {
      ta += acnt[(size_t)bb * Mn + m];
      te += ecnt[(size_t)bb * Mn + m];
    }
    float av = (float)ta * (1.f / 32768.f);
    float ev = (float)te * (1.f / 32768.f);
    float ea = av * logf(av + 1e-10f);
    float ee = ev * logf(ev + 1e-10f);
    #pragma unroll
    for (int off = 1; off <= 32; off <<= 1) { ea += __shfl_xor(ea, off); ee += __shfl_xor(ee, off); }
    __shared__ float r2[4][2];
    const int ln = t & 63, w = t >> 6;
    if (ln == 0) { r2[w][0] = ea; r2[w][1] = ee; }
    __syncthreads();
    if (t == 0) {
      atomicAdd(ws + OFF_ENT + 0, r2[0][0] + r2[1][0] + r2[2][0] + r2[3][0]);
      atomicAdd(ws + OFF_ENT + 1, r2[0][1] + r2[1][1] + r2[2][1] + r2[3][1]);
    }
  }
}

// ---------------- Scode: 256 blocks (i, j-quarter) ----------------
__global__ __launch_bounds__(256) void kC1(float* __restrict__ ws) {
  const int blk = blockIdx.x;
  const int i = blk >> 2, jq = blk & 3;
  const int t = threadIdx.x;
  const int jj = t >> 4, q = t & 15;
  const int j = jq * 16 + jj;
  const float* ai  = ws + OFF_APHN + (size_t)i * Mn;
  const float* ei  = ws + OFF_EPHN + (size_t)i * Mn;
  const float* lej = ws + OFF_LE + (size_t)j * Mn;
  const float* laj = ws + OFF_LA + (size_t)j * Mn;
  float s = 0.f;
  #pragma unroll 4
  for (int m = q * 64; m < q * 64 + 64; ++m)
    s += ai[m] * lej[m] + ei[m] * laj[m];
  s += __shfl_xor(s, 1); s += __shfl_xor(s, 2);
  s += __shfl_xor(s, 4); s += __shfl_xor(s, 8);
  if (q == 0) ws[OFF_SCODE + i * 64 + j] = s;
}

// ---------------- finalize ----------------
__global__ __launch_bounds__(256) void kFin(float* __restrict__ ws, float* __restrict__ out) {
  __shared__ float sc[4096];
  __shared__ float red[256];
  __shared__ float rterm[64];
  __shared__ float maxv;
  const int tid = threadIdx.x;
  for (int i = tid; i < 4096; i += 256) sc[i] = ws[OFF_SCODE + i];
  __syncthreads();

  float mx = -3.0e38f;
  for (int i = tid; i < 4096; i += 256) mx = fmaxf(mx, -sc[i]);
  red[tid] = mx; __syncthreads();
  for (int s = 128; s > 0; s >>= 1) {
    if (tid < s) red[tid] = fmaxf(red[tid], red[tid + s]);
    __syncthreads();
  }
  if (tid == 0) maxv = red[0];
  __syncthreads();
  const float Max = maxv;

  if (tid < 64) {
    float rs = 0.f;
    for (int j = 0; j < 64; ++j) rs += expf(sc[tid * 64 + j] + Max);
    float dg = expf(sc[tid * 64 + tid] + Max);
    rterm[tid] = logf(dg / (rs + 1e-5f));
  }
  __syncthreads();
  if (tid == 0) {
    float s = 0.f;
    for (int i = 0; i < 64; ++i) s += rterm[i];
    out[OUT_SCALARS + 4] = -0.5f * s / 64.f;
  }
  if (tid == 1) {
    const float* lat = ws + OFF_LAT;
    const float inv = 1.f / 8388608.f;
    float a_e = lat[0] * inv, ae = lat[1] * inv, e_e = lat[2] * inv, ea = lat[3] * inv;
    out[OUT_SCALARS + 0] = 0.25f * (2.f * a_e + ae);
    out[OUT_SCALARS + 1] = 0.25f * (2.f * e_e + ea);
  }
  if (tid == 2) out[OUT_SCALARS + 2] = expf(-ws[OFF_ENT + 0]);
  if (tid == 3) out[OUT_SCALARS + 3] = expf(-ws[OFF_ENT + 1]);
  if (tid == 4) {
    const int* ma = (const int*)ws + OFF_MODEA;
    const int* me = (const int*)ws + OFF_MODEE;
    int eq = 0;
    for (int b2 = 0; b2 < 64; ++b2) eq += (ma[b2] == me[b2]) ? 1 : 0;
    out[OUT_SCALARS + 5] = (float)eq;
  }
}

extern "C" void kernel_launch(void* const* d_in, const int* in_sizes, int n_in,
                              void* d_out, int out_size, void* d_ws, size_t ws_size,
                              hipStream_t stream) {
  const float* audio = (const float*)d_in[0];
  const float* eeg   = (const float*)d_in[1];
  const float* emb   = (const float*)d_in[2];
  float* out = (float*)d_out;
  float* ws  = (float*)d_ws;
  (void)in_sizes; (void)n_in; (void)out_size; (void)ws_size;

  hipMemsetAsync(d_ws, 0, (size_t)ZERO_FLOATS * sizeof(float), stream);
  hipLaunchKernelGGL(kPrepE, dim3(32), dim3(256), 0, stream, emb, ws);
  hipLaunchKernelGGL(kMain, dim3(Nn / 16), dim3(512), 0, stream, audio, eeg, emb, out, ws);
  hipLaunchKernelGGL(kAux, dim3(324), dim3(256), 0, stream, ws);
  hipLaunchKernelGGL(kC1, dim3(256), dim3(256), 0, stream, ws);
  hipLaunchKernelGGL(kFin, dim3(1), dim3(256), 0, stream, ws, out);
}